// Round 7
// baseline (1076.274 us; speedup 1.0000x reference)
//
#include <hip/hip_runtime.h>
#include <hip/hip_bf16.h>

typedef __hip_bfloat16 bf16;
typedef short s16x8 __attribute__((ext_vector_type(8)));
typedef float f32x4 __attribute__((ext_vector_type(4)));

// Problem constants
#define HN 4
#define DM 256
#define KF 1024
#define FFD 1024
#define LL 2048
#define BB 4
#define NN (LL * BB)   // 8192
#define HD (HN * DM)   // 1024

__device__ __forceinline__ float b2f(unsigned short u) {
    unsigned v = ((unsigned)u) << 16; float f; __builtin_memcpy(&f, &v, 4); return f;
}
__device__ __forceinline__ unsigned short f2b(float f) {
    bf16 b = (bf16)f; unsigned short u; __builtin_memcpy(&u, &b, 2); return u;
}

// ---------------- reductions ----------------
__device__ __forceinline__ float waveReduceSum(float v) {
    for (int o = 32; o; o >>= 1) v += __shfl_down(v, o, 64);
    return v;
}
__device__ __forceinline__ float waveReduceMax(float v) {
    for (int o = 32; o; o >>= 1) v = fmaxf(v, __shfl_down(v, o, 64));
    return v;
}
__device__ __forceinline__ float blockReduceSum(float v) {
    __shared__ float sh[4];
    v = waveReduceSum(v);
    __syncthreads();
    if ((threadIdx.x & 63) == 0) sh[threadIdx.x >> 6] = v;
    __syncthreads();
    return sh[0] + sh[1] + sh[2] + sh[3];
}
__device__ __forceinline__ float blockReduceMax(float v) {
    __shared__ float sh[4];
    v = waveReduceMax(v);
    __syncthreads();
    if ((threadIdx.x & 63) == 0) sh[threadIdx.x >> 6] = v;
    __syncthreads();
    return fmaxf(fmaxf(sh[0], sh[1]), fmaxf(sh[2], sh[3]));
}

__global__ void sentinel_kernel(float* out, float val) {
    if (threadIdx.x == 0 && blockIdx.x == 0) out[0] = val;
}

// global_load_lds: body only in device pass (host pass: empty stub, never called).
// NOTE: do NOT gate host-side launch logic on __has_builtin — it is 0 in the
// host pass and silently disables launches (round-2 lesson).
__device__ __forceinline__ void gll16(const void* g, void* l) {
#if defined(__HIP_DEVICE_COMPILE__)
    __builtin_amdgcn_global_load_lds(
        (const __attribute__((address_space(1))) unsigned int*)g,
        (__attribute__((address_space(3))) unsigned int*)l, 16, 0, 0);
#endif
}

#define VMC(n) asm volatile("s_waitcnt vmcnt(" #n ")" ::: "memory")
#define LGKM0() asm volatile("s_waitcnt lgkmcnt(0)" ::: "memory")

// T1 XCD-aware chunked swizzle over the (x,y) tile plane. Bijective when
// n2 % 8 == 0 (all our grids); identity otherwise. Correctness-invariant.
__device__ __forceinline__ void xcd_swz(int& bx, int& by) {
    int gx = gridDim.x;
    int n2 = gx * gridDim.y;
    if ((n2 & 7) == 0) {
        int f = bx + by * gx;
        int fs = (f & 7) * (n2 >> 3) + (f >> 3);
        bx = fs % gx;
        by = fs / gx;
    }
}

// ---------------- 256x256 8-phase MFMA GEMM (bf16 operands only) ----------------
// Verified rounds 4/6: 0 bank conflicts, absmax-identical. This round: + T1 swizzle.
__global__ __launch_bounds__(512) void gemm256(
    const bf16* __restrict__ A, int lda, long sA,
    const bf16* __restrict__ Bv, int ldb, long sB,
    void* __restrict__ C, int cF32, int ldc, long sC,
    int Kc,
    const float* __restrict__ bias, long sBias,
    const void* __restrict__ aux, int auxType, int ldaux, long sAux,
    float accSign, int relu)
{
    const int z = blockIdx.z;
    const bf16* Ah = A + (long)z * sA;
    const bf16* Bh = Bv + (long)z * sB;
    float* Cf = (float*)C + (long)z * sC;
    bf16*  Ch = (bf16*)C + (long)z * sC;
    const float* biasp = bias ? (bias + (long)z * sBias) : nullptr;
    const float* auxf = (auxType == 1) ? ((const float*)aux + (long)z * sAux) : nullptr;
    const bf16*  auxh = (auxType == 2) ? ((const bf16*)aux + (long)z * sAux) : nullptr;

    __shared__ __align__(16) bf16 As[2][256 * 64];   // 64 KiB
    __shared__ __align__(16) bf16 Bs[2][256 * 64];   // 64 KiB

    const int tid  = threadIdx.x;
    const int lane = tid & 63;
    const int wid  = __builtin_amdgcn_readfirstlane(tid >> 6);
    const int wm   = wid >> 2;          // 0..1  (row half, 128 rows)
    const int wn   = wid & 3;           // 0..3  (col quarter, 64 cols)
    const int lrow = lane & 15;
    const int quad = lane >> 4;
    int bx = blockIdx.x, by = blockIdx.y;
    xcd_swz(bx, by);
    const int m0 = bx * 256;
    const int n0 = by * 256;

    // staging: each gll16 covers 8 rows x 128B (wave-uniform LDS base + lane*16B)
    const int srow8  = wid * 8 + (lane >> 3);                    // 0..63
    const int scolsw = ((lane & 7) * 8) ^ ((srow8 & 7) << 3);    // pre-swizzled source col
    const bf16* Aorg = Ah + (long)m0 * lda;
    const bf16* Borg = Bh + (long)n0 * ldb;

    // fragment-read constants (swizzled LDS col; row&7 == lane&7 for all frag rows)
    const int colx = (lane & 7) << 3;
    const int kc0 = (quad * 8) ^ colx;
    const int kc1 = (32 + quad * 8) ^ colx;

    f32x4 acc[8][4] = {};
    s16x8 afr[4][2], bfr[4][2];

    const int nk = Kc >> 6;

    auto stg = [&](const bf16* org, int ld, bf16* lds, int k0, int h) {
#pragma unroll
        for (int j = 0; j < 2; j++) {
            int rl = h * 128 + j * 64 + srow8;
            gll16((const void*)(org + (long)rl * ld + k0 + scolsw),
                  (void*)(lds + (h * 128 + j * 64 + wid * 8) * 64));
        }
    };

    // ---- prologue: stage tiles 0 and 1, wait tile 0 (tile1's 8 loads in flight) ----
    stg(Aorg, lda, As[0], 0, 0); stg(Aorg, lda, As[0], 0, 1);
    stg(Borg, ldb, Bs[0], 0, 0); stg(Borg, ldb, Bs[0], 0, 1);
    if (nk > 1) {
        stg(Aorg, lda, As[1], 64, 0); stg(Aorg, lda, As[1], 64, 1);
        stg(Borg, ldb, Bs[1], 64, 0); stg(Borg, ldb, Bs[1], 64, 1);
        VMC(8);
    } else {
        VMC(0);
    }
    __builtin_amdgcn_s_barrier();

    for (int t = 0; t < nk; ++t) {
        const int s = t & 1;
        const bf16* Acur = As[s];
        const bf16* Bcur = Bs[s];
        bf16* Anxt = As[s ^ 1];
        bf16* Bslot = Bs[s];
        const bool stA = (t >= 1) && (t + 1 < nk);   // A[t+1] (tiles 0,1 staged in prologue)
        const bool stB = (t + 2 < nk);               // B[t+2] into freed B region of slot s

        // ---------- phase 1: af(mi0-3) + bf(ni0-1); stage A[t+1]h0 ----------
#pragma unroll
        for (int mi = 0; mi < 4; mi++) {
            int r = (wm * 128 + mi * 16 + lrow) * 64;
            afr[mi][0] = *(const s16x8*)&Acur[r + kc0];
            afr[mi][1] = *(const s16x8*)&Acur[r + kc1];
        }
#pragma unroll
        for (int ni = 0; ni < 2; ni++) {
            int r = (wn * 64 + ni * 16 + lrow) * 64;
            bfr[ni][0] = *(const s16x8*)&Bcur[r + kc0];
            bfr[ni][1] = *(const s16x8*)&Bcur[r + kc1];
        }
        if (stA) stg(Aorg, lda, Anxt, (t + 1) << 6, 0);
        __builtin_amdgcn_s_barrier();
        LGKM0();
        __builtin_amdgcn_s_setprio(1);
#pragma unroll
        for (int mi = 0; mi < 4; mi++)
#pragma unroll
            for (int ni = 0; ni < 2; ni++)
#pragma unroll
                for (int ks = 0; ks < 2; ks++)
                    acc[mi][ni] = __builtin_amdgcn_mfma_f32_16x16x32_bf16(afr[mi][ks], bfr[ni][ks], acc[mi][ni], 0, 0, 0);
        __builtin_amdgcn_s_setprio(0);
        __builtin_amdgcn_s_barrier();

        // ---------- phase 2: bf(ni2-3); stage A[t+1]h1 ----------
#pragma unroll
        for (int ni = 0; ni < 2; ni++) {
            int r = (wn * 64 + (2 + ni) * 16 + lrow) * 64;
            bfr[2 + ni][0] = *(const s16x8*)&Bcur[r + kc0];
            bfr[2 + ni][1] = *(const s16x8*)&Bcur[r + kc1];
        }
        if (stA) stg(Aorg, lda, Anxt, (t + 1) << 6, 1);
        __builtin_amdgcn_s_barrier();
        LGKM0();
        __builtin_amdgcn_s_setprio(1);
#pragma unroll
        for (int mi = 0; mi < 4; mi++)
#pragma unroll
            for (int ni = 0; ni < 2; ni++)
#pragma unroll
                for (int ks = 0; ks < 2; ks++)
                    acc[mi][2 + ni] = __builtin_amdgcn_mfma_f32_16x16x32_bf16(afr[mi][ks], bfr[2 + ni][ks], acc[mi][2 + ni], 0, 0, 0);
        __builtin_amdgcn_s_setprio(0);
        __builtin_amdgcn_s_barrier();

        // ---------- phase 3: af(mi4-7); stage B[t+2]h0 (B[t] reads drained at ph2 barrier) ----------
#pragma unroll
        for (int mi = 0; mi < 4; mi++) {
            int r = (wm * 128 + 64 + mi * 16 + lrow) * 64;
            afr[mi][0] = *(const s16x8*)&Acur[r + kc0];
            afr[mi][1] = *(const s16x8*)&Acur[r + kc1];
        }
        if (stB) stg(Borg, ldb, Bslot, (t + 2) << 6, 0);
        __builtin_amdgcn_s_barrier();
        LGKM0();
        __builtin_amdgcn_s_setprio(1);
#pragma unroll
        for (int mi = 0; mi < 4; mi++)
#pragma unroll
            for (int ni = 0; ni < 2; ni++)
#pragma unroll
                for (int ks = 0; ks < 2; ks++)
                    acc[4 + mi][ni] = __builtin_amdgcn_mfma_f32_16x16x32_bf16(afr[mi][ks], bfr[ni][ks], acc[4 + mi][ni], 0, 0, 0);
        __builtin_amdgcn_s_setprio(0);
        __builtin_amdgcn_s_barrier();

        // ---------- phase 4: no reads; stage B[t+2]h1; counted vmcnt ----------
        if (stB) stg(Borg, ldb, Bslot, (t + 2) << 6, 1);
        __builtin_amdgcn_s_barrier();
        __builtin_amdgcn_s_setprio(1);
#pragma unroll
        for (int mi = 0; mi < 4; mi++)
#pragma unroll
            for (int ni = 0; ni < 2; ni++)
#pragma unroll
                for (int ks = 0; ks < 2; ks++)
                    acc[4 + mi][2 + ni] = __builtin_amdgcn_mfma_f32_16x16x32_bf16(afr[mi][ks], bfr[2 + ni][ks], acc[4 + mi][2 + ni], 0, 0, 0);
        __builtin_amdgcn_s_setprio(0);
        // vmcnt(4): tile t+1 (A+B, 8 oldest) drained; B[t+2]'s 4 loads stay in flight
        if (stB) { VMC(4); } else { VMC(0); }
        __builtin_amdgcn_s_barrier();
    }

    // epilogue: C/D layout col = lane&15, row = quad*4 + i (verified)
#pragma unroll
    for (int mi = 0; mi < 8; mi++) {
#pragma unroll
        for (int ni = 0; ni < 4; ni++) {
            int col = n0 + wn * 64 + ni * 16 + lrow;
            float bvl = biasp ? biasp[col] : 0.0f;
#pragma unroll
            for (int i = 0; i < 4; i++) {
                int row = m0 + wm * 128 + mi * 16 + quad * 4 + i;
                float v = accSign * acc[mi][ni][i] + bvl;
                if (auxType == 1) v += auxf[(long)row * ldaux + col];
                else if (auxType == 2) v += (float)auxh[(long)row * ldaux + col];
                if (relu) v = fmaxf(v, 0.0f);
                if (cF32) Cf[(long)row * ldc + col] = v;
                else Ch[(long)row * ldc + col] = (bf16)v;
            }
        }
    }
}

// ---------------- 128-tile MFMA GEMM ----------------
// bf16 path: 3-buffer 2-deep prefetch, raw builtin s_barrier + counted vmcnt
// (T4, m218 — confirmed a win round 6). This round: + T1 swizzle.
template<int BN>
__global__ __launch_bounds__(256) void gemm_nt(
    const void* __restrict__ A, int aF32, int lda, long sA,
    const void* __restrict__ Bv, int bF32, int ldb, long sB,
    void* __restrict__ C, int cF32, int ldc, long sC,
    int Kc,
    const float* __restrict__ bias, long sBias,
    const void* __restrict__ aux, int auxType, int ldaux, long sAux,
    float accSign, int relu)
{
    constexpr int NI = BN / 32;   // B fragments per wave
    constexpr int WN = BN / 2;    // cols per wn-wave
    const int z = blockIdx.z;
    const float* Af = (const float*)A + (long)z * sA;
    const bf16*  Ah = (const bf16*)A + (long)z * sA;
    const float* Bf = (const float*)Bv + (long)z * sB;
    const bf16*  Bh = (const bf16*)Bv + (long)z * sB;
    float* Cf = (float*)C + (long)z * sC;
    bf16*  Ch = (bf16*)C + (long)z * sC;
    const float* biasp = bias ? (bias + (long)z * sBias) : nullptr;
    const float* auxf = (auxType == 1) ? ((const float*)aux + (long)z * sAux) : nullptr;
    const bf16*  auxh = (auxType == 2) ? ((const bf16*)aux + (long)z * sAux) : nullptr;

    __shared__ __align__(16) bf16 As[3][128 * 32];
    __shared__ __align__(16) bf16 Bs[3][BN * 32];

    const int tid = threadIdx.x;
    const int lane = tid & 63;
    const int wv = __builtin_amdgcn_readfirstlane(tid >> 6);
    const int wm = (tid >> 6) & 1;
    const int wn = (tid >> 6) >> 1;
    const int lrow = lane & 15;
    const int quad = lane >> 4;
    int bx = blockIdx.x, by = blockIdx.y;
    xcd_swz(bx, by);
    const int m0 = bx * 128;
    const int n0 = by * BN;
    const int srow = tid >> 1;
    const int scol = (tid & 1) * 16;
    const int drow = wv * 16 + (lane >> 2);
    const int dcol = (lane & 3) * 8;

    f32x4 acc[4][NI] = {};

    if (!aF32 && !bF32) {
        // bf16 operands: 3-buffer counted-vmcnt pipeline
        const int nk = Kc >> 5;
        auto stage = [&](int t) {
            const int buf = t % 3;
            const int k0 = t << 5;
            const bf16* a0 = Ah + (long)(m0 + drow) * lda + k0 + dcol;
            gll16((const void*)a0, (void*)&As[buf][wv * 512]);
            gll16((const void*)(a0 + (long)lda * 64), (void*)&As[buf][2048 + wv * 512]);
            const bf16* b0 = Bh + (long)(n0 + drow) * ldb + k0 + dcol;
            gll16((const void*)b0, (void*)&Bs[buf][wv * 512]);
            if (BN == 128)
                gll16((const void*)(b0 + (long)ldb * 64), (void*)&Bs[buf][2048 + wv * 512]);
        };
        stage(0);
        if (nk > 1) {
            stage(1);
            if constexpr (BN == 128) { VMC(4); } else { VMC(3); }
        } else {
            VMC(0);
        }
        __builtin_amdgcn_s_barrier();
        for (int t = 0; t < nk; ++t) {
            const int cur = t % 3;
            if (t + 2 < nk) stage(t + 2);
            s16x8 af[4], bfg[NI];
#pragma unroll
            for (int mi = 0; mi < 4; mi++)
                af[mi] = *(const s16x8*)&As[cur][(wm * 64 + mi * 16 + lrow) * 32 + quad * 8];
#pragma unroll
            for (int ni = 0; ni < NI; ni++)
                bfg[ni] = *(const s16x8*)&Bs[cur][(wn * WN + ni * 16 + lrow) * 32 + quad * 8];
#pragma unroll
            for (int mi = 0; mi < 4; mi++)
#pragma unroll
                for (int ni = 0; ni < NI; ni++)
                    acc[mi][ni] = __builtin_amdgcn_mfma_f32_16x16x32_bf16(af[mi], bfg[ni], acc[mi][ni], 0, 0, 0);
            // drain stage(t+1) (oldest L), keep stage(t+2) in flight
            if (t + 2 < nk) {
                if constexpr (BN == 128) { VMC(4); } else { VMC(3); }
            } else {
                VMC(0);
            }
            __builtin_amdgcn_s_barrier();
        }
    } else {
        // f32 or mixed operands, single buffer (bf16 side staged via gll)
        for (int k0 = 0; k0 < Kc; k0 += 32) {
            uint4 av0, av1, bv0, bv1;
            if (aF32) {
                const float* ag = Af + (long)(m0 + srow) * lda + k0 + scol;
                ushort t[16];
#pragma unroll
                for (int j = 0; j < 4; j++) {
                    float4 f = *(const float4*)(ag + 4 * j);
                    t[4*j] = f2b(f.x); t[4*j+1] = f2b(f.y); t[4*j+2] = f2b(f.z); t[4*j+3] = f2b(f.w);
                }
                av0 = *(const uint4*)&t[0]; av1 = *(const uint4*)&t[8];
            }
            if (bF32) {
                if (srow < BN) {
                    const float* bg = Bf + (long)(n0 + srow) * ldb + k0 + scol;
                    ushort t[16];
#pragma unroll
                    for (int j = 0; j < 4; j++) {
                        float4 f = *(const float4*)(bg + 4 * j);
                        t[4*j] = f2b(f.x); t[4*j+1] = f2b(f.y); t[4*j+2] = f2b(f.z); t[4*j+3] = f2b(f.w);
                    }
                    bv0 = *(const uint4*)&t[0]; bv1 = *(const uint4*)&t[8];
                }
            }
            __syncthreads();
            if (aF32) {
                *(uint4*)&As[0][srow * 32 + scol] = av0;
                *(uint4*)&As[0][srow * 32 + scol + 8] = av1;
            } else {
                gll16((const void*)(Ah + (long)(m0 + drow) * lda + k0 + dcol), (void*)&As[0][wv * 512]);
                gll16((const void*)(Ah + (long)(m0 + 64 + drow) * lda + k0 + dcol), (void*)&As[0][2048 + wv * 512]);
            }
            if (bF32) {
                if (srow < BN) {
                    *(uint4*)&Bs[0][srow * 32 + scol] = bv0;
                    *(uint4*)&Bs[0][srow * 32 + scol + 8] = bv1;
                }
            } else {
                gll16((const void*)(Bh + (long)(n0 + drow) * ldb + k0 + dcol), (void*)&Bs[0][wv * 512]);
                if (BN == 128)
                    gll16((const void*)(Bh + (long)(n0 + 64 + drow) * ldb + k0 + dcol), (void*)&Bs[0][2048 + wv * 512]);
            }
            __syncthreads();

            s16x8 af[4], bfg[NI];
#pragma unroll
            for (int mi = 0; mi < 4; mi++)
                af[mi] = *(const s16x8*)&As[0][(wm * 64 + mi * 16 + lrow) * 32 + quad * 8];
#pragma unroll
            for (int ni = 0; ni < NI; ni++)
                bfg[ni] = *(const s16x8*)&Bs[0][(wn * WN + ni * 16 + lrow) * 32 + quad * 8];
#pragma unroll
            for (int mi = 0; mi < 4; mi++)
#pragma unroll
                for (int ni = 0; ni < NI; ni++)
                    acc[mi][ni] = __builtin_amdgcn_mfma_f32_16x16x32_bf16(af[mi], bfg[ni], acc[mi][ni], 0, 0, 0);
        }
    }

    // epilogue
#pragma unroll
    for (int mi = 0; mi < 4; mi++) {
#pragma unroll
        for (int ni = 0; ni < NI; ni++) {
            int col = n0 + wn * WN + ni * 16 + lrow;
            float bvl = biasp ? biasp[col] : 0.0f;
#pragma unroll
            for (int i = 0; i < 4; i++) {
                int row = m0 + wm * 64 + mi * 16 + quad * 4 + i;
                float v = accSign * acc[mi][ni][i] + bvl;
                if (auxType == 1) v += auxf[(long)row * ldaux + col];
                else if (auxType == 2) v += (float)auxh[(long)row * ldaux + col];
                if (relu) v = fmaxf(v, 0.0f);
                if (cF32) Cf[(long)row * ldc + col] = v;
                else Ch[(long)row * ldc + col] = (bf16)v;
            }
        }
    }
}

// ---------------- conversions ----------------
__global__ __launch_bounds__(256) void cvt4(const float* __restrict__ in, bf16* __restrict__ out, int n4) {
    int i = blockIdx.x * 256 + threadIdx.x;
    if (i < n4) {
        float4 f = ((const float4*)in)[i];
        ushort4 u; u.x = f2b(f.x); u.y = f2b(f.y); u.z = f2b(f.z); u.w = f2b(f.w);
        ((ushort4*)out)[i] = u;
    }
}

struct WCvt {
    const float* in[16];
    bf16* out[16];
    int n4[16];
};
__global__ __launch_bounds__(256) void cvt_weights(WCvt wc) {
    int t = blockIdx.y;
    int n4 = wc.n4[t];
    const float4* in = (const float4*)wc.in[t];
    ushort4* out = (ushort4*)wc.out[t];
    for (int i = blockIdx.x * 256 + threadIdx.x; i < n4; i += gridDim.x * 256) {
        float4 f = in[i];
        ushort4 u; u.x = f2b(f.x); u.y = f2b(f.y); u.z = f2b(f.z); u.w = f2b(f.w);
        out[i] = u;
    }
}

// ---------------- elementwise / normalization ----------------
__global__ __launch_bounds__(256) void l2norm_rows(bf16* __restrict__ Q) {
    bf16* q = Q + (long)blockIdx.x * KF;
    ushort4 u = ((ushort4*)q)[threadIdx.x];
    float v0 = b2f(u.x), v1 = b2f(u.y), v2 = b2f(u.z), v3 = b2f(u.w);
    float ss = blockReduceSum(v0 * v0 + v1 * v1 + v2 * v2 + v3 * v3);
    float inv = 1.0f / fmaxf(sqrtf(ss), 1e-12f);
    u.x = f2b(v0 * inv); u.y = f2b(v1 * inv); u.z = f2b(v2 * inv); u.w = f2b(v3 * inv);
    ((ushort4*)q)[threadIdx.x] = u;
}

// merged Q/K l2norm, planar layout: plane y (0=Q, 1=K), row x
__global__ __launch_bounds__(256) void l2norm2(bf16* __restrict__ QK) {
    bf16* q = QK + (long)blockIdx.y * ((long)NN * KF) + (long)blockIdx.x * KF;
    ushort4 u = ((ushort4*)q)[threadIdx.x];
    float v0 = b2f(u.x), v1 = b2f(u.y), v2 = b2f(u.z), v3 = b2f(u.w);
    float ss = blockReduceSum(v0 * v0 + v1 * v1 + v2 * v2 + v3 * v3);
    float inv = 1.0f / fmaxf(sqrtf(ss), 1e-12f);
    u.x = f2b(v0 * inv); u.y = f2b(v1 * inv); u.z = f2b(v2 * inv); u.w = f2b(v3 * inv);
    ((ushort4*)q)[threadIdx.x] = u;
}

__global__ __launch_bounds__(256) void softmax_rows(bf16* __restrict__ P) {
    bf16* p = P + (long)blockIdx.x * LL;
    ushort4 a = ((ushort4*)p)[2 * threadIdx.x];
    ushort4 b = ((ushort4*)p)[2 * threadIdx.x + 1];
    float v[8] = {b2f(a.x), b2f(a.y), b2f(a.z), b2f(a.w), b2f(b.x), b2f(b.y), b2f(b.z), b2f(b.w)};
    float mx = -1e30f;
#pragma unroll
    for (int i = 0; i < 8; i++) mx = fmaxf(mx, v[i]);
    mx = blockReduceMax(mx);
    float s = 0.0f;
#pragma unroll
    for (int i = 0; i < 8; i++) { v[i] = __expf(v[i] - mx); s += v[i]; }
    s = blockReduceSum(s);
    float inv = 1.0f / s;
    a.x = f2b(v[0]*inv); a.y = f2b(v[1]*inv); a.z = f2b(v[2]*inv); a.w = f2b(v[3]*inv);
    b.x = f2b(v[4]*inv); b.y = f2b(v[5]*inv); b.z = f2b(v[6]*inv); b.w = f2b(v[7]*inv);
    ((ushort4*)p)[2 * threadIdx.x] = a;
    ((ushort4*)p)[2 * threadIdx.x + 1] = b;
}

__global__ __launch_bounds__(256) void zero_cs(float* __restrict__ cs) {
    cs[blockIdx.x * 256 + threadIdx.x] = 0.0f;
}

__global__ __launch_bounds__(256) void colsum2(const bf16* __restrict__ P, float* __restrict__ cs) {
    int col = blockIdx.x * 256 + threadIdx.x;
    int rc = blockIdx.y;
    int b = blockIdx.z;
    const bf16* p = P + (long)b * LL * LL + (long)rc * 128 * LL + col;
    float s = 0.0f;
#pragma unroll 4
    for (int r = 0; r < 128; r++) s += (float)p[(long)r * LL];
    atomicAdd(&cs[(long)b * LL + col], s);
}

__global__ __launch_bounds__(256) void scale_vt(bf16* __restrict__ vt, const float* __restrict__ cs) {
    int e = blockIdx.x, b = blockIdx.y;
    bf16* row = vt + ((long)b * DM + e) * LL;
    const float* c = cs + (long)b * LL;
#pragma unroll
    for (int i = 0; i < 8; i++) {
        int m = threadIdx.x + i * 256;
        row[m] = (bf16)((float)row[m] / (1e-9f + c[m]));
    }
}

__global__ __launch_bounds__(256) void ln_rows(const bf16* __restrict__ in, void* __restrict__ out,
                                               int outF32,
                                               const float* __restrict__ g, const float* __restrict__ b,
                                               const float* __restrict__ aux) {
    long base = (long)blockIdx.x * 256;
    float v = (float)in[base + threadIdx.x];
    if (aux) v += aux[base + threadIdx.x];
    float mean = blockReduceSum(v) * (1.0f / 256.0f);
    float d = v - mean;
    float var = blockReduceSum(d * d) * (1.0f / 256.0f);
    float o = d * rsqrtf(var + 1e-5f) * g[threadIdx.x] + b[threadIdx.x];
    if (outF32) ((float*)out)[base + threadIdx.x] = o;
    else ((bf16*)out)[base + threadIdx.x] = (bf16)o;
}

__global__ __launch_bounds__(256) void ln_cat(bf16* __restrict__ cat, const float* __restrict__ g,
                                              const float* __restrict__ bb) {
    long n = blockIdx.x;
    int h = blockIdx.y;
    bf16* x = cat + n * HD + (long)h * DM;
    float v = (float)x[threadIdx.x];
    float mean = blockReduceSum(v) * (1.0f / 256.0f);
    float d = v - mean;
    float var = blockReduceSum(d * d) * (1.0f / 256.0f);
    x[threadIdx.x] = (bf16)(d * rsqrtf(var + 1e-5f) * g[h * DM + threadIdx.x] + bb[h * DM + threadIdx.x]);
}

// ---------------- host ----------------
extern "C" void kernel_launch(void* const* d_in, const int* in_sizes, int n_in,
                              void* d_out, int out_size, void* d_ws, size_t ws_size,
                              hipStream_t stream) {
    const float* src  = (const float*)d_in[0];
    const float* WK   = (const float*)d_in[1];
    const float* WQ   = (const float*)d_in[2];
    const float* WV   = (const float*)d_in[3];
    const float* TC   = (const float*)d_in[4];
    const float* ENw1 = (const float*)d_in[5];
    const float* ENb1 = (const float*)d_in[6];
    const float* ENw2 = (const float*)d_in[7];
    const float* ENb2 = (const float*)d_in[8];
    const float* ENg  = (const float*)d_in[9];
    const float* ENbt = (const float*)d_in[10];
    const float* Wout = (const float*)d_in[11];
    const float* L1w  = (const float*)d_in[12];
    const float* L1b  = (const float*)d_in[13];
    const float* L2w  = (const float*)d_in[14];
    const float* L2b  = (const float*)d_in[15];
    const float* N1g  = (const float*)d_in[16];
    const float* N1b  = (const float*)d_in[17];
    const float* N2g  = (const float*)d_in[18];
    const float* N2b  = (const float*)d_in[19];

    const size_t COMPACT_FLOOR = 34700000;
    const size_t FAST_FLOOR  = 92307456;
    const size_t FASTW_FLOOR = 92307456 + 11010048;
    if (ws_size < COMPACT_FLOOR || out_size != NN * DM || n_in != 20) {
        float val;
        if (n_in != 20) val = 32768.0f + (float)n_in;
        else if (out_size != NN * DM) val = 49152.0f;
        else val = 16384.0f + 128.0f * (float)(unsigned)(ws_size >> 20);
        sentinel_kernel<<<1, 64, 0, stream>>>((float*)d_out, val);
        return;
    }

    char* w = (char*)d_ws;
    auto G = [&](const void* A, int aF, int lda, long sA,
                 const void* B, int bF, int ldb, long sB,
                 void* C, int cF, int ldc, long sC,
                 int M, int Nn, int Kc, int nb,
                 const float* bias, long sBias,
                 const void* aux, int auxT, int ldaux, long sAux,
                 float sgn, int relu) {
        gemm_nt<128><<<dim3(M / 128, Nn / 128, nb), dim3(256), 0, stream>>>(
            A, aF, lda, sA, B, bF, ldb, sB, C, cF, ldc, sC, Kc,
            bias, sBias, aux, auxT, ldaux, sAux, sgn, relu);
    };
    auto G64 = [&](const void* A, int aF, int lda, long sA,
                 const void* B, int bF, int ldb, long sB,
                 void* C, int cF, int ldc, long sC,
                 int M, int Nn, int Kc, int nb,
                 const float* bias, long sBias,
                 const void* aux, int auxT, int ldaux, long sAux,
                 float sgn, int relu) {
        gemm_nt<64><<<dim3(M / 128, Nn / 64, nb), dim3(256), 0, stream>>>(
            A, aF, lda, sA, B, bF, ldb, sB, C, cF, ldc, sC, Kc,
            bias, sBias, aux, auxT, ldaux, sAux, sgn, relu);
    };
    auto G2 = [&](const void* A, int lda, long sA,
                  const void* B, int ldb, long sB,
                  void* C, int cF, int ldc, long sC,
                  int M, int Nn, int Kc, int nb,
                  const float* bias, long sBias,
                  const void* aux, int auxT, int ldaux, long sAux,
                  float sgn, int relu) {
        gemm256<<<dim3(M / 256, Nn / 256, nb), dim3(512), 0, stream>>>(
            (const bf16*)A, lda, sA, (const bf16*)B, ldb, sB, C, cF, ldc, sC, Kc,
            bias, sBias, aux, auxT, ldaux, sAux, sgn, relu);
    };

    if (ws_size >= FAST_FLOOR) {
        // ======== FAST PATH ========
        bf16*  Sb  = (bf16*)(w + 0);
        bf16*  Q   = (bf16*)(w + 4194304);     // 16 MB, planar
        bf16*  K   = (bf16*)(w + 20971520);    // 16 MB, planar (= Q + NN*KF elems)
        bf16*  Vt  = (bf16*)(w + 37748736);
        bf16*  P   = (bf16*)(w + 41943040);
        bf16*  Su  = (bf16*)(w + 75497472);
        float* Cs  = (float*)(w + 92274688);
        bf16* Ru = Q; bf16* Hid = K; bf16* Cat = P;
        bf16* Attn = Vt; bf16* Xln = Su; bf16* Ffh = Q; bf16* Yp = Vt;

        const int haveWb = (ws_size >= FASTW_FLOOR) ? 1 : 0;
        char* wb = w + 92307456;
        bf16* WQKb  = (bf16*)(wb + 0);          // 4MB: per head [WQ_h(1024x256); WK_h(1024x256)]
        bf16* WVb   = (bf16*)(wb + 4194304);
        bf16* TCb   = (bf16*)(wb + 4718592);
        bf16* ENw1b = (bf16*)(wb + 5242880);
        bf16* ENw2b = (bf16*)(wb + 7340032);
        bf16* Woutb = (bf16*)(wb + 9437184);
        bf16* L1wb  = (bf16*)(wb + 9961472);
        bf16* L2wb  = (bf16*)(wb + 10485760);
        if (haveWb) {
            WCvt wc;
            for (int h = 0; h < HN; h++) {
                wc.in[2*h]   = WQ + (long)h * KF * DM; wc.out[2*h]   = WQKb + (long)h * 2048 * DM;            wc.n4[2*h]   = 65536;
                wc.in[2*h+1] = WK + (long)h * KF * DM; wc.out[2*h+1] = WQKb + (long)h * 2048 * DM + KF * DM;  wc.n4[2*h+1] = 65536;
            }
            wc.in[8]  = WV;   wc.out[8]  = WVb;   wc.n4[8]  = 65536;
            wc.in[9]  = TC;   wc.out[9]  = TCb;   wc.n4[9]  = 65536;
            wc.in[10] = ENw1; wc.out[10] = ENw1b; wc.n4[10] = 262144;
            wc.in[11] = ENw2; wc.out[11] = ENw2b; wc.n4[11] = 262144;
            wc.in[12] = Wout; wc.out[12] = Woutb; wc.n4[12] = 65536;
            wc.in[13] = L1w;  wc.out[13] = L1wb;  wc.n4[13] = 65536;
            wc.in[14] = L2w;  wc.out[14] = L2wb;  wc.n4[14] = 65536;
            cvt_weights<<<dim3(256, 15), 256, 0, stream>>>(wc);
        }
        const int wF = haveWb ? 0 : 1;
        auto WP = [&](const void* f32p, const void* b16p, long off) {
            return haveWb ? (const void*)((const bf16*)b16p + off)
                          : (const void*)((const float*)f32p + off);
        };

        cvt4<<<2048, 256, 0, stream>>>(src, Sb, NN * DM / 4);

        for (int h = 0; h < HN; h++) {
            if (haveWb) {
                // merged Q+K projection via z-batch: z=0 -> WQ_h -> Q plane,
                // z=1 -> WK_h -> K plane. Planar outputs keep the P-GEMM's
                // 8KB row stride (round-6 lesson: 16KB stride cost 35% BW).
                // grid (32,4,2) = 256 blocks = full GPU.
                G2(Sb, DM, 0, WQKb + (long)h * 2048 * DM, DM, (long)KF * DM,
                   Q, 0, KF, (long)NN * KF,
                   NN, KF, DM, 2, nullptr, 0, nullptr, 0, 0, 0, 1.0f, 0);
            } else {
                G(Sb, 0, DM, 0, WQ + (long)h * KF * DM, 1, DM, 0, Q, 0, KF, 0,
                  NN, KF, DM, 1, nullptr, 0, nullptr, 0, 0, 0, 1.0f, 0);
                G(Sb, 0, DM, 0, WK + (long)h * KF * DM, 1, DM, 0, K, 0, KF, 0,
                  NN, KF, DM, 1, nullptr, 0, nullptr, 0, 0, 0, 1.0f, 0);
            }
            G64(WP(WV, WVb, (long)h * DM * DM), wF, DM, 0, Sb, 0, BB * DM, DM,
              Vt, 0, LL, (long)DM * LL,
              DM, LL, DM, BB, nullptr, 0, nullptr, 0, 0, 0, 1.0f, 0);
            l2norm2<<<dim3(NN, 2), 256, 0, stream>>>(Q);
            // P = Q K^T, separate planar Q/K (verified round-4 form, 51.5us)
            G2(Q, BB * KF, KF, K, BB * KF, KF, P, 0, LL, (long)LL * LL,
               LL, LL, KF, BB, nullptr, 0, nullptr, 0, 0, 0, 1.0f, 0);
            softmax_rows<<<BB * LL, 256, 0, stream>>>(P);
            zero_cs<<<BB * LL / 256, 256, 0, stream>>>(Cs);
            colsum2<<<dim3(LL / 256, 16, BB), 256, 0, stream>>>(P, Cs);
            scale_vt<<<dim3(DM, BB), 256, 0, stream>>>(Vt, Cs);
            G64(P, 0, LL, (long)LL * LL, Vt, 0, LL, (long)DM * LL,
              Su + (long)h * NN * DM, 0, BB * DM, DM,
              LL, DM, LL, BB, nullptr, 0, Sb, 2, BB * DM, DM, -1.0f, 0);
        }
        G(Su, 0, DM, (long)NN * DM, WP(TC, TCb, 0), wF, DM, (long)DM * DM,
          Ru, 0, DM, (long)NN * DM,
          NN, DM, DM, HN, nullptr, 0, nullptr, 0, 0, 0, 1.0f, 1);
        for (int h = 0; h < HN; h++) {
            G(Ru + (long)h * NN * DM, 0, DM, 0, WP(ENw1, ENw1b, (long)h * FFD * DM), wF, DM, 0,
              Hid, 0, FFD, 0, NN, FFD, DM, 1, ENb1 + (long)h * FFD, 0, nullptr, 0, 0, 0, 1.0f, 1);
            G64(Hid, 0, FFD, 0, WP(ENw2, ENw2b, (long)h * DM * FFD), wF, FFD, 0,
              Cat + (long)h * DM, 0, HD, 0, NN, DM, FFD, 1,
              ENb2 + (long)h * DM, 0, Ru + (long)h * NN * DM, 2, DM, 0, 1.0f, 0);
        }
        ln_cat<<<dim3(NN, HN), 256, 0, stream>>>(Cat, ENg, ENbt);
        G64(Cat, 0, HD, 0, WP(Wout, Woutb, 0), wF, HD, 0, Attn, 0, DM, 0,
          NN, DM, HD, 1, nullptr, 0, nullptr, 0, 0, 0, 1.0f, 0);
        ln_rows<<<NN, 256, 0, stream>>>(Attn, Xln, 0, N1g, N1b, src);
        G(Xln, 0, DM, 0, WP(L1w, L1wb, 0), wF, DM, 0, Ffh, 0, FFD, 0,
          NN, FFD, DM, 1, L1b, 0, nullptr, 0, 0, 0, 1.0f, 1);
        G64(Ffh, 0, FFD, 0, WP(L2w, L2wb, 0), wF, FFD, 0, Yp, 0, DM, 0,
          NN, DM, FFD, 1, L2b, 0, Xln, 2, DM, 0, 1.0f, 0);
        ln_rows<<<NN, 256, 0, stream>>>(Yp, (float*)d_out, 1, N2g, N2b, nullptr);
    } else {
        // ======== COMPACT PATH ========
        bf16*  S0 = (bf16*)(w + 0);
        bf16*  S1 = (bf16*)(w + 16777216);
        bf16*  S2 = (bf16*)(w + 20971520);
        bf16*  S3 = (bf16*)(w + 25165824);
        bf16*  S4 = (bf16*)(w + 26214400);
        bf16*  S5 = (bf16*)(w + 30408704);
        float* Cs = (float*)(w + 34603008);

        for (int h = 0; h < HN; h++) {
            for (int b = 0; b < BB; b++) {
                G(src + b * DM, 1, BB * DM, 0, WQ + (long)h * KF * DM, 1, DM, 0,
                  S1, 0, KF, 0, LL, KF, DM, 1, nullptr, 0, nullptr, 0, 0, 0, 1.0f, 0);
                G(src + b * DM, 1, BB * DM, 0, WK + (long)h * KF * DM, 1, DM, 0,
                  S2, 0, KF, 0, LL, KF, DM, 1, nullptr, 0, nullptr, 0, 0, 0, 1.0f, 0);
                G(WV + (long)h * DM * DM, 1, DM, 0, src + b * DM, 1, BB * DM, 0,
                  S3, 0, LL, 0, DM, LL, DM, 1, nullptr, 0, nullptr, 0, 0, 0, 1.0f, 0);
                l2norm_rows<<<LL, 256, 0, stream>>>(S1);
                l2norm_rows<<<LL, 256, 0, stream>>>(S2);
                G(S1, 0, KF, 0, S2, 0, KF, 0, S0, 0, LL, 0,
                  LL, LL, KF, 1, nullptr, 0, nullptr, 0, 0, 0, 1.0f, 0);
                softmax_rows<<<LL, 256, 0, stream>>>(S0);
                zero_cs<<<LL / 256, 256, 0, stream>>>(Cs);
                colsum2<<<dim3(LL / 256, 16, 1), 256, 0, stream>>>(S0, Cs);
                scale_vt<<<dim3(DM, 1), 256, 0, stream>>>(S3, Cs);
                G(S0, 0, LL, 0, S3, 0, LL, 0, S4 + b * DM, 0, BB * DM, 0,
                  LL, DM, LL, 1, nullptr, 0, src + b * DM, 1, BB * DM, 0, -1.0f, 0);
            }
            G(S4, 0, DM, 0, TC + (long)h * DM * DM, 1, DM, 0, S1, 0, DM, 0,
              NN, DM, DM, 1, nullptr, 0, nullptr, 0, 0, 0, 1.0f, 1);
            G(S1, 0, DM, 0, ENw1 + (long)h * FFD * DM, 1, DM, 0, S0, 0, FFD, 0,
              NN, FFD, DM, 1, ENb1 + (long)h * FFD, 0, nullptr, 0, 0, 0, 1.0f, 1);
            G(S0, 0, FFD, 0, ENw2 + (long)h * DM * FFD, 1, FFD, 0, S2, 0, DM, 0,
              NN, DM, FFD, 1, ENb2 + (long)h * DM, 0, S1, 2, DM, 0, 1.0f, 0);
            ln_rows<<<NN, 256, 0, stream>>>(S2, S2, 0, ENg + (long)h * DM, ENbt + (long)h * DM, nullptr);
            G(S2, 0, DM, 0, Wout + (long)h * DM, 1, HD, 0, S5, 0, DM, 0,
              NN, DM, DM, 1, nullptr, 0, (h == 0) ? nullptr : (const void*)S5,
              (h == 0) ? 0 : 2, DM, 0, 1.0f, 0);
        }
        ln_rows<<<NN, 256, 0, stream>>>(S5, S1, 0, N1g, N1b, src);
        G(S1, 0, DM, 0, L1w, 1, DM, 0, S0, 0, FFD, 0,
          NN, FFD, DM, 1, L1b, 0, nullptr, 0, 0, 0, 1.0f, 1);
        G(S0, 0, FFD, 0, L2w, 1, FFD, 0, S2, 0, DM, 0,
          NN, DM, FFD, 1, L2b, 0, S1, 2, DM, 0, 1.0f, 0);
        ln_rows<<<NN, 256, 0, stream>>>(S2, (float*)d_out, 1, N2g, N2b, nullptr);
    }
}

// Round 8
// 1063.076 us; speedup vs baseline: 1.0124x; 1.0124x over previous
//
#include <hip/hip_runtime.h>
#include <hip/hip_bf16.h>

typedef __hip_bfloat16 bf16;
typedef short s16x8 __attribute__((ext_vector_type(8)));
typedef float f32x4 __attribute__((ext_vector_type(4)));

// Problem constants
#define HN 4
#define DM 256
#define KF 1024
#define FFD 1024
#define LL 2048
#define BB 4
#define NN (LL * BB)   // 8192
#define HD (HN * DM)   // 1024

__device__ __forceinline__ float b2f(unsigned short u) {
    unsigned v = ((unsigned)u) << 16; float f; __builtin_memcpy(&f, &v, 4); return f;
}
__device__ __forceinline__ unsigned short f2b(float f) {
    bf16 b = (bf16)f; unsigned short u; __builtin_memcpy(&u, &b, 2); return u;
}

// ---------------- reductions ----------------
__device__ __forceinline__ float waveReduceSum(float v) {
    for (int o = 32; o; o >>= 1) v += __shfl_down(v, o, 64);
    return v;
}
__device__ __forceinline__ float waveReduceMax(float v) {
    for (int o = 32; o; o >>= 1) v = fmaxf(v, __shfl_down(v, o, 64));
    return v;
}
__device__ __forceinline__ float blockReduceSum(float v) {
    __shared__ float sh[4];
    v = waveReduceSum(v);
    __syncthreads();
    if ((threadIdx.x & 63) == 0) sh[threadIdx.x >> 6] = v;
    __syncthreads();
    return sh[0] + sh[1] + sh[2] + sh[3];
}
__device__ __forceinline__ float blockReduceMax(float v) {
    __shared__ float sh[4];
    v = waveReduceMax(v);
    __syncthreads();
    if ((threadIdx.x & 63) == 0) sh[threadIdx.x >> 6] = v;
    __syncthreads();
    return fmaxf(fmaxf(sh[0], sh[1]), fmaxf(sh[2], sh[3]));
}

__global__ void sentinel_kernel(float* out, float val) {
    if (threadIdx.x == 0 && blockIdx.x == 0) out[0] = val;
}

// global_load_lds: body only in device pass (host pass: empty stub, never called).
// NOTE: do NOT gate host-side launch logic on __has_builtin — it is 0 in the
// host pass and silently disables launches (round-2 lesson).
// NOTE (round 7 lesson): XCD-aware block swizzle HURTS here (+19% on the
// non-P launches) — the working set is L3-resident so there is no HBM
// refetch to save, and per-grid-shape swizzling destroys producer→consumer
// L2 affinity between chained kernels. Do not re-add without FETCH_SIZE
// evidence of refetch.
__device__ __forceinline__ void gll16(const void* g, void* l) {
#if defined(__HIP_DEVICE_COMPILE__)
    __builtin_amdgcn_global_load_lds(
        (const __attribute__((address_space(1))) unsigned int*)g,
        (__attribute__((address_space(3))) unsigned int*)l, 16, 0, 0);
#endif
}

#define VMC(n) asm volatile("s_waitcnt vmcnt(" #n ")" ::: "memory")
#define LGKM0() asm volatile("s_waitcnt lgkmcnt(0)" ::: "memory")

// ---------------- 256x256 8-phase MFMA GEMM (bf16 operands only) ----------------
// Verified rounds 4/7: 0 bank conflicts, absmax-identical.
__global__ __launch_bounds__(512) void gemm256(
    const bf16* __restrict__ A, int lda, long sA,
    const bf16* __restrict__ Bv, int ldb, long sB,
    void* __restrict__ C, int cF32, int ldc, long sC,
    int Kc,
    const float* __restrict__ bias, long sBias,
    const void* __restrict__ aux, int auxType, int ldaux, long sAux,
    float accSign, int relu)
{
    const int z = blockIdx.z;
    const bf16* Ah = A + (long)z * sA;
    const bf16* Bh = Bv + (long)z * sB;
    float* Cf = (float*)C + (long)z * sC;
    bf16*  Ch = (bf16*)C + (long)z * sC;
    const float* biasp = bias ? (bias + (long)z * sBias) : nullptr;
    const float* auxf = (auxType == 1) ? ((const float*)aux + (long)z * sAux) : nullptr;
    const bf16*  auxh = (auxType == 2) ? ((const bf16*)aux + (long)z * sAux) : nullptr;

    __shared__ __align__(16) bf16 As[2][256 * 64];   // 64 KiB
    __shared__ __align__(16) bf16 Bs[2][256 * 64];   // 64 KiB

    const int tid  = threadIdx.x;
    const int lane = tid & 63;
    const int wid  = __builtin_amdgcn_readfirstlane(tid >> 6);
    const int wm   = wid >> 2;          // 0..1  (row half, 128 rows)
    const int wn   = wid & 3;           // 0..3  (col quarter, 64 cols)
    const int lrow = lane & 15;
    const int quad = lane >> 4;
    const int m0 = blockIdx.x * 256;
    const int n0 = blockIdx.y * 256;

    // staging: each gll16 covers 8 rows x 128B (wave-uniform LDS base + lane*16B)
    const int srow8  = wid * 8 + (lane >> 3);                    // 0..63
    const int scolsw = ((lane & 7) * 8) ^ ((srow8 & 7) << 3);    // pre-swizzled source col
    const bf16* Aorg = Ah + (long)m0 * lda;
    const bf16* Borg = Bh + (long)n0 * ldb;

    // fragment-read constants (swizzled LDS col; row&7 == lane&7 for all frag rows)
    const int colx = (lane & 7) << 3;
    const int kc0 = (quad * 8) ^ colx;
    const int kc1 = (32 + quad * 8) ^ colx;

    f32x4 acc[8][4] = {};
    s16x8 afr[4][2], bfr[4][2];

    const int nk = Kc >> 6;

    auto stg = [&](const bf16* org, int ld, bf16* lds, int k0, int h) {
#pragma unroll
        for (int j = 0; j < 2; j++) {
            int rl = h * 128 + j * 64 + srow8;
            gll16((const void*)(org + (long)rl * ld + k0 + scolsw),
                  (void*)(lds + (h * 128 + j * 64 + wid * 8) * 64));
        }
    };

    // ---- prologue: stage tiles 0 and 1, wait tile 0 (tile1's 8 loads in flight) ----
    stg(Aorg, lda, As[0], 0, 0); stg(Aorg, lda, As[0], 0, 1);
    stg(Borg, ldb, Bs[0], 0, 0); stg(Borg, ldb, Bs[0], 0, 1);
    if (nk > 1) {
        stg(Aorg, lda, As[1], 64, 0); stg(Aorg, lda, As[1], 64, 1);
        stg(Borg, ldb, Bs[1], 64, 0); stg(Borg, ldb, Bs[1], 64, 1);
        VMC(8);
    } else {
        VMC(0);
    }
    __builtin_amdgcn_s_barrier();

    for (int t = 0; t < nk; ++t) {
        const int s = t & 1;
        const bf16* Acur = As[s];
        const bf16* Bcur = Bs[s];
        bf16* Anxt = As[s ^ 1];
        bf16* Bslot = Bs[s];
        const bool stA = (t >= 1) && (t + 1 < nk);   // A[t+1] (tiles 0,1 staged in prologue)
        const bool stB = (t + 2 < nk);               // B[t+2] into freed B region of slot s

        // ---------- phase 1: af(mi0-3) + bf(ni0-1); stage A[t+1]h0 ----------
#pragma unroll
        for (int mi = 0; mi < 4; mi++) {
            int r = (wm * 128 + mi * 16 + lrow) * 64;
            afr[mi][0] = *(const s16x8*)&Acur[r + kc0];
            afr[mi][1] = *(const s16x8*)&Acur[r + kc1];
        }
#pragma unroll
        for (int ni = 0; ni < 2; ni++) {
            int r = (wn * 64 + ni * 16 + lrow) * 64;
            bfr[ni][0] = *(const s16x8*)&Bcur[r + kc0];
            bfr[ni][1] = *(const s16x8*)&Bcur[r + kc1];
        }
        if (stA) stg(Aorg, lda, Anxt, (t + 1) << 6, 0);
        __builtin_amdgcn_s_barrier();
        LGKM0();
        __builtin_amdgcn_s_setprio(1);
#pragma unroll
        for (int mi = 0; mi < 4; mi++)
#pragma unroll
            for (int ni = 0; ni < 2; ni++)
#pragma unroll
                for (int ks = 0; ks < 2; ks++)
                    acc[mi][ni] = __builtin_amdgcn_mfma_f32_16x16x32_bf16(afr[mi][ks], bfr[ni][ks], acc[mi][ni], 0, 0, 0);
        __builtin_amdgcn_s_setprio(0);
        __builtin_amdgcn_s_barrier();

        // ---------- phase 2: bf(ni2-3); stage A[t+1]h1 ----------
#pragma unroll
        for (int ni = 0; ni < 2; ni++) {
            int r = (wn * 64 + (2 + ni) * 16 + lrow) * 64;
            bfr[2 + ni][0] = *(const s16x8*)&Bcur[r + kc0];
            bfr[2 + ni][1] = *(const s16x8*)&Bcur[r + kc1];
        }
        if (stA) stg(Aorg, lda, Anxt, (t + 1) << 6, 1);
        __builtin_amdgcn_s_barrier();
        LGKM0();
        __builtin_amdgcn_s_setprio(1);
#pragma unroll
        for (int mi = 0; mi < 4; mi++)
#pragma unroll
            for (int ni = 0; ni < 2; ni++)
#pragma unroll
                for (int ks = 0; ks < 2; ks++)
                    acc[mi][2 + ni] = __builtin_amdgcn_mfma_f32_16x16x32_bf16(afr[mi][ks], bfr[2 + ni][ks], acc[mi][2 + ni], 0, 0, 0);
        __builtin_amdgcn_s_setprio(0);
        __builtin_amdgcn_s_barrier();

        // ---------- phase 3: af(mi4-7); stage B[t+2]h0 (B[t] reads drained at ph2 barrier) ----------
#pragma unroll
        for (int mi = 0; mi < 4; mi++) {
            int r = (wm * 128 + 64 + mi * 16 + lrow) * 64;
            afr[mi][0] = *(const s16x8*)&Acur[r + kc0];
            afr[mi][1] = *(const s16x8*)&Acur[r + kc1];
        }
        if (stB) stg(Borg, ldb, Bslot, (t + 2) << 6, 0);
        __builtin_amdgcn_s_barrier();
        LGKM0();
        __builtin_amdgcn_s_setprio(1);
#pragma unroll
        for (int mi = 0; mi < 4; mi++)
#pragma unroll
            for (int ni = 0; ni < 2; ni++)
#pragma unroll
                for (int ks = 0; ks < 2; ks++)
                    acc[4 + mi][ni] = __builtin_amdgcn_mfma_f32_16x16x32_bf16(afr[mi][ks], bfr[ni][ks], acc[4 + mi][ni], 0, 0, 0);
        __builtin_amdgcn_s_setprio(0);
        __builtin_amdgcn_s_barrier();

        // ---------- phase 4: no reads; stage B[t+2]h1; counted vmcnt ----------
        if (stB) stg(Borg, ldb, Bslot, (t + 2) << 6, 1);
        __builtin_amdgcn_s_barrier();
        __builtin_amdgcn_s_setprio(1);
#pragma unroll
        for (int mi = 0; mi < 4; mi++)
#pragma unroll
            for (int ni = 0; ni < 2; ni++)
#pragma unroll
                for (int ks = 0; ks < 2; ks++)
                    acc[4 + mi][2 + ni] = __builtin_amdgcn_mfma_f32_16x16x32_bf16(afr[mi][ks], bfr[2 + ni][ks], acc[4 + mi][2 + ni], 0, 0, 0);
        __builtin_amdgcn_s_setprio(0);
        // vmcnt(4): tile t+1 (A+B, 8 oldest) drained; B[t+2]'s 4 loads stay in flight
        if (stB) { VMC(4); } else { VMC(0); }
        __builtin_amdgcn_s_barrier();
    }

    // epilogue: C/D layout col = lane&15, row = quad*4 + i (verified)
#pragma unroll
    for (int mi = 0; mi < 8; mi++) {
#pragma unroll
        for (int ni = 0; ni < 4; ni++) {
            int col = n0 + wn * 64 + ni * 16 + lrow;
            float bvl = biasp ? biasp[col] : 0.0f;
#pragma unroll
            for (int i = 0; i < 4; i++) {
                int row = m0 + wm * 128 + mi * 16 + quad * 4 + i;
                float v = accSign * acc[mi][ni][i] + bvl;
                if (auxType == 1) v += auxf[(long)row * ldaux + col];
                else if (auxType == 2) v += (float)auxh[(long)row * ldaux + col];
                if (relu) v = fmaxf(v, 0.0f);
                if (cF32) Cf[(long)row * ldc + col] = v;
                else Ch[(long)row * ldc + col] = (bf16)v;
            }
        }
    }
}

// ---------------- 128-tile MFMA GEMM ----------------
// bf16 path: 3-buffer 2-deep prefetch, raw builtin s_barrier + counted vmcnt
// (T4, m218 — confirmed a win round 6).
template<int BN>
__global__ __launch_bounds__(256) void gemm_nt(
    const void* __restrict__ A, int aF32, int lda, long sA,
    const void* __restrict__ Bv, int bF32, int ldb, long sB,
    void* __restrict__ C, int cF32, int ldc, long sC,
    int Kc,
    const float* __restrict__ bias, long sBias,
    const void* __restrict__ aux, int auxType, int ldaux, long sAux,
    float accSign, int relu)
{
    constexpr int NI = BN / 32;   // B fragments per wave
    constexpr int WN = BN / 2;    // cols per wn-wave
    const int z = blockIdx.z;
    const float* Af = (const float*)A + (long)z * sA;
    const bf16*  Ah = (const bf16*)A + (long)z * sA;
    const float* Bf = (const float*)Bv + (long)z * sB;
    const bf16*  Bh = (const bf16*)Bv + (long)z * sB;
    float* Cf = (float*)C + (long)z * sC;
    bf16*  Ch = (bf16*)C + (long)z * sC;
    const float* biasp = bias ? (bias + (long)z * sBias) : nullptr;
    const float* auxf = (auxType == 1) ? ((const float*)aux + (long)z * sAux) : nullptr;
    const bf16*  auxh = (auxType == 2) ? ((const bf16*)aux + (long)z * sAux) : nullptr;

    __shared__ __align__(16) bf16 As[3][128 * 32];
    __shared__ __align__(16) bf16 Bs[3][BN * 32];

    const int tid = threadIdx.x;
    const int lane = tid & 63;
    const int wv = __builtin_amdgcn_readfirstlane(tid >> 6);
    const int wm = (tid >> 6) & 1;
    const int wn = (tid >> 6) >> 1;
    const int lrow = lane & 15;
    const int quad = lane >> 4;
    const int m0 = blockIdx.x * 128;
    const int n0 = blockIdx.y * BN;
    const int srow = tid >> 1;
    const int scol = (tid & 1) * 16;
    const int drow = wv * 16 + (lane >> 2);
    const int dcol = (lane & 3) * 8;

    f32x4 acc[4][NI] = {};

    if (!aF32 && !bF32) {
        // bf16 operands: 3-buffer counted-vmcnt pipeline
        const int nk = Kc >> 5;
        auto stage = [&](int t) {
            const int buf = t % 3;
            const int k0 = t << 5;
            const bf16* a0 = Ah + (long)(m0 + drow) * lda + k0 + dcol;
            gll16((const void*)a0, (void*)&As[buf][wv * 512]);
            gll16((const void*)(a0 + (long)lda * 64), (void*)&As[buf][2048 + wv * 512]);
            const bf16* b0 = Bh + (long)(n0 + drow) * ldb + k0 + dcol;
            gll16((const void*)b0, (void*)&Bs[buf][wv * 512]);
            if (BN == 128)
                gll16((const void*)(b0 + (long)ldb * 64), (void*)&Bs[buf][2048 + wv * 512]);
        };
        stage(0);
        if (nk > 1) {
            stage(1);
            if constexpr (BN == 128) { VMC(4); } else { VMC(3); }
        } else {
            VMC(0);
        }
        __builtin_amdgcn_s_barrier();
        for (int t = 0; t < nk; ++t) {
            const int cur = t % 3;
            if (t + 2 < nk) stage(t + 2);
            s16x8 af[4], bfg[NI];
#pragma unroll
            for (int mi = 0; mi < 4; mi++)
                af[mi] = *(const s16x8*)&As[cur][(wm * 64 + mi * 16 + lrow) * 32 + quad * 8];
#pragma unroll
            for (int ni = 0; ni < NI; ni++)
                bfg[ni] = *(const s16x8*)&Bs[cur][(wn * WN + ni * 16 + lrow) * 32 + quad * 8];
#pragma unroll
            for (int mi = 0; mi < 4; mi++)
#pragma unroll
                for (int ni = 0; ni < NI; ni++)
                    acc[mi][ni] = __builtin_amdgcn_mfma_f32_16x16x32_bf16(af[mi], bfg[ni], acc[mi][ni], 0, 0, 0);
            // drain stage(t+1) (oldest L), keep stage(t+2) in flight
            if (t + 2 < nk) {
                if constexpr (BN == 128) { VMC(4); } else { VMC(3); }
            } else {
                VMC(0);
            }
            __builtin_amdgcn_s_barrier();
        }
    } else {
        // f32 or mixed operands, single buffer (bf16 side staged via gll)
        for (int k0 = 0; k0 < Kc; k0 += 32) {
            uint4 av0, av1, bv0, bv1;
            if (aF32) {
                const float* ag = Af + (long)(m0 + srow) * lda + k0 + scol;
                ushort t[16];
#pragma unroll
                for (int j = 0; j < 4; j++) {
                    float4 f = *(const float4*)(ag + 4 * j);
                    t[4*j] = f2b(f.x); t[4*j+1] = f2b(f.y); t[4*j+2] = f2b(f.z); t[4*j+3] = f2b(f.w);
                }
                av0 = *(const uint4*)&t[0]; av1 = *(const uint4*)&t[8];
            }
            if (bF32) {
                if (srow < BN) {
                    const float* bg = Bf + (long)(n0 + srow) * ldb + k0 + scol;
                    ushort t[16];
#pragma unroll
                    for (int j = 0; j < 4; j++) {
                        float4 f = *(const float4*)(bg + 4 * j);
                        t[4*j] = f2b(f.x); t[4*j+1] = f2b(f.y); t[4*j+2] = f2b(f.z); t[4*j+3] = f2b(f.w);
                    }
                    bv0 = *(const uint4*)&t[0]; bv1 = *(const uint4*)&t[8];
                }
            }
            __syncthreads();
            if (aF32) {
                *(uint4*)&As[0][srow * 32 + scol] = av0;
                *(uint4*)&As[0][srow * 32 + scol + 8] = av1;
            } else {
                gll16((const void*)(Ah + (long)(m0 + drow) * lda + k0 + dcol), (void*)&As[0][wv * 512]);
                gll16((const void*)(Ah + (long)(m0 + 64 + drow) * lda + k0 + dcol), (void*)&As[0][2048 + wv * 512]);
            }
            if (bF32) {
                if (srow < BN) {
                    *(uint4*)&Bs[0][srow * 32 + scol] = bv0;
                    *(uint4*)&Bs[0][srow * 32 + scol + 8] = bv1;
                }
            } else {
                gll16((const void*)(Bh + (long)(n0 + drow) * ldb + k0 + dcol), (void*)&Bs[0][wv * 512]);
                if (BN == 128)
                    gll16((const void*)(Bh + (long)(n0 + 64 + drow) * ldb + k0 + dcol), (void*)&Bs[0][2048 + wv * 512]);
            }
            __syncthreads();

            s16x8 af[4], bfg[NI];
#pragma unroll
            for (int mi = 0; mi < 4; mi++)
                af[mi] = *(const s16x8*)&As[0][(wm * 64 + mi * 16 + lrow) * 32 + quad * 8];
#pragma unroll
            for (int ni = 0; ni < NI; ni++)
                bfg[ni] = *(const s16x8*)&Bs[0][(wn * WN + ni * 16 + lrow) * 32 + quad * 8];
#pragma unroll
            for (int mi = 0; mi < 4; mi++)
#pragma unroll
                for (int ni = 0; ni < NI; ni++)
                    acc[mi][ni] = __builtin_amdgcn_mfma_f32_16x16x32_bf16(af[mi], bfg[ni], acc[mi][ni], 0, 0, 0);
        }
    }

    // epilogue
#pragma unroll
    for (int mi = 0; mi < 4; mi++) {
#pragma unroll
        for (int ni = 0; ni < NI; ni++) {
            int col = n0 + wn * WN + ni * 16 + lrow;
            float bvl = biasp ? biasp[col] : 0.0f;
#pragma unroll
            for (int i = 0; i < 4; i++) {
                int row = m0 + wm * 64 + mi * 16 + quad * 4 + i;
                float v = accSign * acc[mi][ni][i] + bvl;
                if (auxType == 1) v += auxf[(long)row * ldaux + col];
                else if (auxType == 2) v += (float)auxh[(long)row * ldaux + col];
                if (relu) v = fmaxf(v, 0.0f);
                if (cF32) Cf[(long)row * ldc + col] = v;
                else Ch[(long)row * ldc + col] = (bf16)v;
            }
        }
    }
}

// ---------------- conversions ----------------
__global__ __launch_bounds__(256) void cvt4(const float* __restrict__ in, bf16* __restrict__ out, int n4) {
    int i = blockIdx.x * 256 + threadIdx.x;
    if (i < n4) {
        float4 f = ((const float4*)in)[i];
        ushort4 u; u.x = f2b(f.x); u.y = f2b(f.y); u.z = f2b(f.z); u.w = f2b(f.w);
        ((ushort4*)out)[i] = u;
    }
}

struct WCvt {
    const float* in[16];
    bf16* out[16];
    int n4[16];
};
__global__ __launch_bounds__(256) void cvt_weights(WCvt wc) {
    int t = blockIdx.y;
    int n4 = wc.n4[t];
    const float4* in = (const float4*)wc.in[t];
    ushort4* out = (ushort4*)wc.out[t];
    for (int i = blockIdx.x * 256 + threadIdx.x; i < n4; i += gridDim.x * 256) {
        float4 f = in[i];
        ushort4 u; u.x = f2b(f.x); u.y = f2b(f.y); u.z = f2b(f.z); u.w = f2b(f.w);
        out[i] = u;
    }
}

// ---------------- elementwise / normalization ----------------
__global__ __launch_bounds__(256) void l2norm_rows(bf16* __restrict__ Q) {
    bf16* q = Q + (long)blockIdx.x * KF;
    ushort4 u = ((ushort4*)q)[threadIdx.x];
    float v0 = b2f(u.x), v1 = b2f(u.y), v2 = b2f(u.z), v3 = b2f(u.w);
    float ss = blockReduceSum(v0 * v0 + v1 * v1 + v2 * v2 + v3 * v3);
    float inv = 1.0f / fmaxf(sqrtf(ss), 1e-12f);
    u.x = f2b(v0 * inv); u.y = f2b(v1 * inv); u.z = f2b(v2 * inv); u.w = f2b(v3 * inv);
    ((ushort4*)q)[threadIdx.x] = u;
}

// merged Q/K l2norm, planar layout: plane y (0=Q, 1=K), row x
__global__ __launch_bounds__(256) void l2norm2(bf16* __restrict__ QK) {
    bf16* q = QK + (long)blockIdx.y * ((long)NN * KF) + (long)blockIdx.x * KF;
    ushort4 u = ((ushort4*)q)[threadIdx.x];
    float v0 = b2f(u.x), v1 = b2f(u.y), v2 = b2f(u.z), v3 = b2f(u.w);
    float ss = blockReduceSum(v0 * v0 + v1 * v1 + v2 * v2 + v3 * v3);
    float inv = 1.0f / fmaxf(sqrtf(ss), 1e-12f);
    u.x = f2b(v0 * inv); u.y = f2b(v1 * inv); u.z = f2b(v2 * inv); u.w = f2b(v3 * inv);
    ((ushort4*)q)[threadIdx.x] = u;
}

__global__ __launch_bounds__(256) void softmax_rows(bf16* __restrict__ P) {
    bf16* p = P + (long)blockIdx.x * LL;
    ushort4 a = ((ushort4*)p)[2 * threadIdx.x];
    ushort4 b = ((ushort4*)p)[2 * threadIdx.x + 1];
    float v[8] = {b2f(a.x), b2f(a.y), b2f(a.z), b2f(a.w), b2f(b.x), b2f(b.y), b2f(b.z), b2f(b.w)};
    float mx = -1e30f;
#pragma unroll
    for (int i = 0; i < 8; i++) mx = fmaxf(mx, v[i]);
    mx = blockReduceMax(mx);
    float s = 0.0f;
#pragma unroll
    for (int i = 0; i < 8; i++) { v[i] = __expf(v[i] - mx); s += v[i]; }
    s = blockReduceSum(s);
    float inv = 1.0f / s;
    a.x = f2b(v[0]*inv); a.y = f2b(v[1]*inv); a.z = f2b(v[2]*inv); a.w = f2b(v[3]*inv);
    b.x = f2b(v[4]*inv); b.y = f2b(v[5]*inv); b.z = f2b(v[6]*inv); b.w = f2b(v[7]*inv);
    ((ushort4*)p)[2 * threadIdx.x] = a;
    ((ushort4*)p)[2 * threadIdx.x + 1] = b;
}

__global__ __launch_bounds__(256) void zero_cs(float* __restrict__ cs) {
    cs[blockIdx.x * 256 + threadIdx.x] = 0.0f;
}

__global__ __launch_bounds__(256) void colsum2(const bf16* __restrict__ P, float* __restrict__ cs) {
    int col = blockIdx.x * 256 + threadIdx.x;
    int rc = blockIdx.y;
    int b = blockIdx.z;
    const bf16* p = P + (long)b * LL * LL + (long)rc * 128 * LL + col;
    float s = 0.0f;
#pragma unroll 4
    for (int r = 0; r < 128; r++) s += (float)p[(long)r * LL];
    atomicAdd(&cs[(long)b * LL + col], s);
}

__global__ __launch_bounds__(256) void scale_vt(bf16* __restrict__ vt, const float* __restrict__ cs) {
    int e = blockIdx.x, b = blockIdx.y;
    bf16* row = vt + ((long)b * DM + e) * LL;
    const float* c = cs + (long)b * LL;
#pragma unroll
    for (int i = 0; i < 8; i++) {
        int m = threadIdx.x + i * 256;
        row[m] = (bf16)((float)row[m] / (1e-9f + c[m]));
    }
}

__global__ __launch_bounds__(256) void ln_rows(const bf16* __restrict__ in, void* __restrict__ out,
                                               int outF32,
                                               const float* __restrict__ g, const float* __restrict__ b,
                                               const float* __restrict__ aux) {
    long base = (long)blockIdx.x * 256;
    float v = (float)in[base + threadIdx.x];
    if (aux) v += aux[base + threadIdx.x];
    float mean = blockReduceSum(v) * (1.0f / 256.0f);
    float d = v - mean;
    float var = blockReduceSum(d * d) * (1.0f / 256.0f);
    float o = d * rsqrtf(var + 1e-5f) * g[threadIdx.x] + b[threadIdx.x];
    if (outF32) ((float*)out)[base + threadIdx.x] = o;
    else ((bf16*)out)[base + threadIdx.x] = (bf16)o;
}

__global__ __launch_bounds__(256) void ln_cat(bf16* __restrict__ cat, const float* __restrict__ g,
                                              const float* __restrict__ bb) {
    long n = blockIdx.x;
    int h = blockIdx.y;
    bf16* x = cat + n * HD + (long)h * DM;
    float v = (float)x[threadIdx.x];
    float mean = blockReduceSum(v) * (1.0f / 256.0f);
    float d = v - mean;
    float var = blockReduceSum(d * d) * (1.0f / 256.0f);
    x[threadIdx.x] = (bf16)(d * rsqrtf(var + 1e-5f) * g[h * DM + threadIdx.x] + bb[h * DM + threadIdx.x]);
}

// ---------------- host ----------------
extern "C" void kernel_launch(void* const* d_in, const int* in_sizes, int n_in,
                              void* d_out, int out_size, void* d_ws, size_t ws_size,
                              hipStream_t stream) {
    const float* src  = (const float*)d_in[0];
    const float* WK   = (const float*)d_in[1];
    const float* WQ   = (const float*)d_in[2];
    const float* WV   = (const float*)d_in[3];
    const float* TC   = (const float*)d_in[4];
    const float* ENw1 = (const float*)d_in[5];
    const float* ENb1 = (const float*)d_in[6];
    const float* ENw2 = (const float*)d_in[7];
    const float* ENb2 = (const float*)d_in[8];
    const float* ENg  = (const float*)d_in[9];
    const float* ENbt = (const float*)d_in[10];
    const float* Wout = (const float*)d_in[11];
    const float* L1w  = (const float*)d_in[12];
    const float* L1b  = (const float*)d_in[13];
    const float* L2w  = (const float*)d_in[14];
    const float* L2b  = (const float*)d_in[15];
    const float* N1g  = (const float*)d_in[16];
    const float* N1b  = (const float*)d_in[17];
    const float* N2g  = (const float*)d_in[18];
    const float* N2b  = (const float*)d_in[19];

    const size_t COMPACT_FLOOR = 34700000;
    const size_t FAST_FLOOR  = 92307456;
    const size_t FASTW_FLOOR = 92307456 + 11010048;
    if (ws_size < COMPACT_FLOOR || out_size != NN * DM || n_in != 20) {
        float val;
        if (n_in != 20) val = 32768.0f + (float)n_in;
        else if (out_size != NN * DM) val = 49152.0f;
        else val = 16384.0f + 128.0f * (float)(unsigned)(ws_size >> 20);
        sentinel_kernel<<<1, 64, 0, stream>>>((float*)d_out, val);
        return;
    }

    char* w = (char*)d_ws;
    auto G = [&](const void* A, int aF, int lda, long sA,
                 const void* B, int bF, int ldb, long sB,
                 void* C, int cF, int ldc, long sC,
                 int M, int Nn, int Kc, int nb,
                 const float* bias, long sBias,
                 const void* aux, int auxT, int ldaux, long sAux,
                 float sgn, int relu) {
        gemm_nt<128><<<dim3(M / 128, Nn / 128, nb), dim3(256), 0, stream>>>(
            A, aF, lda, sA, B, bF, ldb, sB, C, cF, ldc, sC, Kc,
            bias, sBias, aux, auxT, ldaux, sAux, sgn, relu);
    };
    auto G64 = [&](const void* A, int aF, int lda, long sA,
                 const void* B, int bF, int ldb, long sB,
                 void* C, int cF, int ldc, long sC,
                 int M, int Nn, int Kc, int nb,
                 const float* bias, long sBias,
                 const void* aux, int auxT, int ldaux, long sAux,
                 float sgn, int relu) {
        gemm_nt<64><<<dim3(M / 128, Nn / 64, nb), dim3(256), 0, stream>>>(
            A, aF, lda, sA, B, bF, ldb, sB, C, cF, ldc, sC, Kc,
            bias, sBias, aux, auxT, ldaux, sAux, sgn, relu);
    };
    auto G2 = [&](const void* A, int lda, long sA,
                  const void* B, int ldb, long sB,
                  void* C, int cF, int ldc, long sC,
                  int M, int Nn, int Kc, int nb,
                  const float* bias, long sBias,
                  const void* aux, int auxT, int ldaux, long sAux,
                  float sgn, int relu) {
        gemm256<<<dim3(M / 256, Nn / 256, nb), dim3(512), 0, stream>>>(
            (const bf16*)A, lda, sA, (const bf16*)B, ldb, sB, C, cF, ldc, sC, Kc,
            bias, sBias, aux, auxT, ldaux, sAux, sgn, relu);
    };

    if (ws_size >= FAST_FLOOR) {
        // ======== FAST PATH ========
        bf16*  Sb  = (bf16*)(w + 0);
        bf16*  Q   = (bf16*)(w + 4194304);     // 16 MB, planar
        bf16*  K   = (bf16*)(w + 20971520);    // 16 MB, planar (= Q + NN*KF elems)
        bf16*  Vt  = (bf16*)(w + 37748736);
        bf16*  P   = (bf16*)(w + 41943040);
        bf16*  Su  = (bf16*)(w + 75497472);
        float* Cs  = (float*)(w + 92274688);
        bf16* Ru = Q; bf16* Hid = K; bf16* Cat = P;
        bf16* Attn = Vt; bf16* Xln = Su; bf16* Ffh = Q; bf16* Yp = Vt;

        const int haveWb = (ws_size >= FASTW_FLOOR) ? 1 : 0;
        char* wb = w + 92307456;
        bf16* WQKb  = (bf16*)(wb + 0);          // 4MB: per head [WQ_h(1024x256); WK_h(1024x256)]
        bf16* WVb   = (bf16*)(wb + 4194304);
        bf16* TCb   = (bf16*)(wb + 4718592);
        bf16* ENw1b = (bf16*)(wb + 5242880);
        bf16* ENw2b = (bf16*)(wb + 7340032);
        bf16* Woutb = (bf16*)(wb + 9437184);
        bf16* L1wb  = (bf16*)(wb + 9961472);
        bf16* L2wb  = (bf16*)(wb + 10485760);
        if (haveWb) {
            WCvt wc;
            for (int h = 0; h < HN; h++) {
                wc.in[2*h]   = WQ + (long)h * KF * DM; wc.out[2*h]   = WQKb + (long)h * 2048 * DM;            wc.n4[2*h]   = 65536;
                wc.in[2*h+1] = WK + (long)h * KF * DM; wc.out[2*h+1] = WQKb + (long)h * 2048 * DM + KF * DM;  wc.n4[2*h+1] = 65536;
            }
            wc.in[8]  = WV;   wc.out[8]  = WVb;   wc.n4[8]  = 65536;
            wc.in[9]  = TC;   wc.out[9]  = TCb;   wc.n4[9]  = 65536;
            wc.in[10] = ENw1; wc.out[10] = ENw1b; wc.n4[10] = 262144;
            wc.in[11] = ENw2; wc.out[11] = ENw2b; wc.n4[11] = 262144;
            wc.in[12] = Wout; wc.out[12] = Woutb; wc.n4[12] = 65536;
            wc.in[13] = L1w;  wc.out[13] = L1wb;  wc.n4[13] = 65536;
            wc.in[14] = L2w;  wc.out[14] = L2wb;  wc.n4[14] = 65536;
            cvt_weights<<<dim3(256, 15), 256, 0, stream>>>(wc);
        }
        const int wF = haveWb ? 0 : 1;
        auto WP = [&](const void* f32p, const void* b16p, long off) {
            return haveWb ? (const void*)((const bf16*)b16p + off)
                          : (const void*)((const float*)f32p + off);
        };

        cvt4<<<2048, 256, 0, stream>>>(src, Sb, NN * DM / 4);

        for (int h = 0; h < HN; h++) {
            if (haveWb) {
                // merged Q+K projection via z-batch: z=0 -> WQ_h -> Q plane,
                // z=1 -> WK_h -> K plane. Planar outputs keep the P-GEMM's
                // 8KB row stride (round-6 lesson: 16KB stride cost 35% BW).
                // grid (32,4,2) = 256 blocks = full GPU.
                G2(Sb, DM, 0, WQKb + (long)h * 2048 * DM, DM, (long)KF * DM,
                   Q, 0, KF, (long)NN * KF,
                   NN, KF, DM, 2, nullptr, 0, nullptr, 0, 0, 0, 1.0f, 0);
            } else {
                G(Sb, 0, DM, 0, WQ + (long)h * KF * DM, 1, DM, 0, Q, 0, KF, 0,
                  NN, KF, DM, 1, nullptr, 0, nullptr, 0, 0, 0, 1.0f, 0);
                G(Sb, 0, DM, 0, WK + (long)h * KF * DM, 1, DM, 0, K, 0, KF, 0,
                  NN, KF, DM, 1, nullptr, 0, nullptr, 0, 0, 0, 1.0f, 0);
            }
            G64(WP(WV, WVb, (long)h * DM * DM), wF, DM, 0, Sb, 0, BB * DM, DM,
              Vt, 0, LL, (long)DM * LL,
              DM, LL, DM, BB, nullptr, 0, nullptr, 0, 0, 0, 1.0f, 0);
            l2norm2<<<dim3(NN, 2), 256, 0, stream>>>(Q);
            // P = Q K^T, separate planar Q/K (verified round-4/7 form)
            G2(Q, BB * KF, KF, K, BB * KF, KF, P, 0, LL, (long)LL * LL,
               LL, LL, KF, BB, nullptr, 0, nullptr, 0, 0, 0, 1.0f, 0);
            softmax_rows<<<BB * LL, 256, 0, stream>>>(P);
            zero_cs<<<BB * LL / 256, 256, 0, stream>>>(Cs);
            colsum2<<<dim3(LL / 256, 16, BB), 256, 0, stream>>>(P, Cs);
            scale_vt<<<dim3(DM, BB), 256, 0, stream>>>(Vt, Cs);
            G64(P, 0, LL, (long)LL * LL, Vt, 0, LL, (long)DM * LL,
              Su + (long)h * NN * DM, 0, BB * DM, DM,
              LL, DM, LL, BB, nullptr, 0, Sb, 2, BB * DM, DM, -1.0f, 0);
        }
        G(Su, 0, DM, (long)NN * DM, WP(TC, TCb, 0), wF, DM, (long)DM * DM,
          Ru, 0, DM, (long)NN * DM,
          NN, DM, DM, HN, nullptr, 0, nullptr, 0, 0, 0, 1.0f, 1);
        for (int h = 0; h < HN; h++) {
            G(Ru + (long)h * NN * DM, 0, DM, 0, WP(ENw1, ENw1b, (long)h * FFD * DM), wF, DM, 0,
              Hid, 0, FFD, 0, NN, FFD, DM, 1, ENb1 + (long)h * FFD, 0, nullptr, 0, 0, 0, 1.0f, 1);
            G64(Hid, 0, FFD, 0, WP(ENw2, ENw2b, (long)h * DM * FFD), wF, FFD, 0,
              Cat + (long)h * DM, 0, HD, 0, NN, DM, FFD, 1,
              ENb2 + (long)h * DM, 0, Ru + (long)h * NN * DM, 2, DM, 0, 1.0f, 0);
        }
        ln_cat<<<dim3(NN, HN), 256, 0, stream>>>(Cat, ENg, ENbt);
        G64(Cat, 0, HD, 0, WP(Wout, Woutb, 0), wF, HD, 0, Attn, 0, DM, 0,
          NN, DM, HD, 1, nullptr, 0, nullptr, 0, 0, 0, 1.0f, 0);
        ln_rows<<<NN, 256, 0, stream>>>(Attn, Xln, 0, N1g, N1b, src);
        G(Xln, 0, DM, 0, WP(L1w, L1wb, 0), wF, DM, 0, Ffh, 0, FFD, 0,
          NN, FFD, DM, 1, L1b, 0, nullptr, 0, 0, 0, 1.0f, 1);
        G64(Ffh, 0, FFD, 0, WP(L2w, L2wb, 0), wF, FFD, 0, Yp, 0, DM, 0,
          NN, DM, FFD, 1, L2b, 0, Xln, 2, DM, 0, 1.0f, 0);
        ln_rows<<<NN, 256, 0, stream>>>(Yp, (float*)d_out, 1, N2g, N2b, nullptr);
    } else {
        // ======== COMPACT PATH ========
        bf16*  S0 = (bf16*)(w + 0);
        bf16*  S1 = (bf16*)(w + 16777216);
        bf16*  S2 = (bf16*)(w + 20971520);
        bf16*  S3 = (bf16*)(w + 25165824);
        bf16*  S4 = (bf16*)(w + 26214400);
        bf16*  S5 = (bf16*)(w + 30408704);
        float* Cs = (float*)(w + 34603008);

        for (int h = 0; h < HN; h++) {
            for (int b = 0; b < BB; b++) {
                G(src + b * DM, 1, BB * DM, 0, WQ + (long)h * KF * DM, 1, DM, 0,
                  S1, 0, KF, 0, LL, KF, DM, 1, nullptr, 0, nullptr, 0, 0, 0, 1.0f, 0);
                G(src + b * DM, 1, BB * DM, 0, WK + (long)h * KF * DM, 1, DM, 0,
                  S2, 0, KF, 0, LL, KF, DM, 1, nullptr, 0, nullptr, 0, 0, 0, 1.0f, 0);
                G(WV + (long)h * DM * DM, 1, DM, 0, src + b * DM, 1, BB * DM, 0,
                  S3, 0, LL, 0, DM, LL, DM, 1, nullptr, 0, nullptr, 0, 0, 0, 1.0f, 0);
                l2norm_rows<<<LL, 256, 0, stream>>>(S1);
                l2norm_rows<<<LL, 256, 0, stream>>>(S2);
                G(S1, 0, KF, 0, S2, 0, KF, 0, S0, 0, LL, 0,
                  LL, LL, KF, 1, nullptr, 0, nullptr, 0, 0, 0, 1.0f, 0);
                softmax_rows<<<LL, 256, 0, stream>>>(S0);
                zero_cs<<<LL / 256, 256, 0, stream>>>(Cs);
                colsum2<<<dim3(LL / 256, 16, 1), 256, 0, stream>>>(S0, Cs);
                scale_vt<<<dim3(DM, 1), 256, 0, stream>>>(S3, Cs);
                G(S0, 0, LL, 0, S3, 0, LL, 0, S4 + b * DM, 0, BB * DM, 0,
                  LL, DM, LL, 1, nullptr, 0, src + b * DM, 1, BB * DM, 0, -1.0f, 0);
            }
            G(S4, 0, DM, 0, TC + (long)h * DM * DM, 1, DM, 0, S1, 0, DM, 0,
              NN, DM, DM, 1, nullptr, 0, nullptr, 0, 0, 0, 1.0f, 1);
            G(S1, 0, DM, 0, ENw1 + (long)h * FFD * DM, 1, DM, 0, S0, 0, FFD, 0,
              NN, FFD, DM, 1, ENb1 + (long)h * FFD, 0, nullptr, 0, 0, 0, 1.0f, 1);
            G(S0, 0, FFD, 0, ENw2 + (long)h * DM * FFD, 1, FFD, 0, S2, 0, DM, 0,
              NN, DM, FFD, 1, ENb2 + (long)h * DM, 0, S1, 2, DM, 0, 1.0f, 0);
            ln_rows<<<NN, 256, 0, stream>>>(S2, S2, 0, ENg + (long)h * DM, ENbt + (long)h * DM, nullptr);
            G(S2, 0, DM, 0, Wout + (long)h * DM, 1, HD, 0, S5, 0, DM, 0,
              NN, DM, DM, 1, nullptr, 0, (h == 0) ? nullptr : (const void*)S5,
              (h == 0) ? 0 : 2, DM, 0, 1.0f, 0);
        }
        ln_rows<<<NN, 256, 0, stream>>>(S5, S1, 0, N1g, N1b, src);
        G(S1, 0, DM, 0, L1w, 1, DM, 0, S0, 0, FFD, 0,
          NN, FFD, DM, 1, L1b, 0, nullptr, 0, 0, 0, 1.0f, 1);
        G(S0, 0, FFD, 0, L2w, 1, FFD, 0, S2, 0, DM, 0,
          NN, DM, FFD, 1, L2b, 0, S1, 2, DM, 0, 1.0f, 0);
        ln_rows<<<NN, 256, 0, stream>>>(S2, (float*)d_out, 1, N2g, N2b, nullptr);
    }
}

// Round 9
// 1041.853 us; speedup vs baseline: 1.0330x; 1.0204x over previous
//
#include <hip/hip_runtime.h>
#include <hip/hip_bf16.h>

typedef __hip_bfloat16 bf16;
typedef short s16x8 __attribute__((ext_vector_type(8)));
typedef float f32x4 __attribute__((ext_vector_type(4)));

// Problem constants
#define HN 4
#define DM 256
#define KF 1024
#define FFD 1024
#define LL 2048
#define BB 4
#define NN (LL * BB)   // 8192
#define HD (HN * DM)   // 1024

__device__ __forceinline__ float b2f(unsigned short u) {
    unsigned v = ((unsigned)u) << 16; float f; __builtin_memcpy(&f, &v, 4); return f;
}
__device__ __forceinline__ unsigned short f2b(float f) {
    bf16 b = (bf16)f; unsigned short u; __builtin_memcpy(&u, &b, 2); return u;
}

// ---------------- reductions ----------------
__device__ __forceinline__ float waveReduceSum(float v) {
    for (int o = 32; o; o >>= 1) v += __shfl_down(v, o, 64);
    return v;
}
__device__ __forceinline__ float waveReduceMax(float v) {
    for (int o = 32; o; o >>= 1) v = fmaxf(v, __shfl_down(v, o, 64));
    return v;
}
__device__ __forceinline__ float blockReduceSum(float v) {
    __shared__ float sh[4];
    v = waveReduceSum(v);
    __syncthreads();
    if ((threadIdx.x & 63) == 0) sh[threadIdx.x >> 6] = v;
    __syncthreads();
    return sh[0] + sh[1] + sh[2] + sh[3];
}
__device__ __forceinline__ float blockReduceMax(float v) {
    __shared__ float sh[4];
    v = waveReduceMax(v);
    __syncthreads();
    if ((threadIdx.x & 63) == 0) sh[threadIdx.x >> 6] = v;
    __syncthreads();
    return fmaxf(fmaxf(sh[0], sh[1]), fmaxf(sh[2], sh[3]));
}

__global__ void sentinel_kernel(float* out, float val) {
    if (threadIdx.x == 0 && blockIdx.x == 0) out[0] = val;
}

// global_load_lds: body only in device pass (host pass: empty stub, never called).
// NOTE: do NOT gate host-side launch logic on __has_builtin — it is 0 in the
// host pass and silently disables launches (round-2 lesson).
// Rounds 6-8 isolated XCD-swizzle effects per kernel class:
//   gemm256 (P-GEMM, 74MB fetch > per-XCD L2): swizzle = +64% (81.6->49.8us).
//   gemm_nt chained launches (L2/L3-resident):  swizzle = -19% (destroys
//   producer->consumer L2 affinity). So swizzle gemm256 ONLY.
__device__ __forceinline__ void gll16(const void* g, void* l) {
#if defined(__HIP_DEVICE_COMPILE__)
    __builtin_amdgcn_global_load_lds(
        (const __attribute__((address_space(1))) unsigned int*)g,
        (__attribute__((address_space(3))) unsigned int*)l, 16, 0, 0);
#endif
}

#define VMC(n) asm volatile("s_waitcnt vmcnt(" #n ")" ::: "memory")
#define LGKM0() asm volatile("s_waitcnt lgkmcnt(0)" ::: "memory")

// T1 XCD-aware chunked swizzle over the (x,y) tile plane. Bijective when
// n2 % 8 == 0; identity otherwise. Correctness-invariant.
__device__ __forceinline__ void xcd_swz(int& bx, int& by) {
    int gx = gridDim.x;
    int n2 = gx * gridDim.y;
    if ((n2 & 7) == 0) {
        int f = bx + by * gx;
        int fs = (f & 7) * (n2 >> 3) + (f >> 3);
        bx = fs % gx;
        by = fs / gx;
    }
}

// ---------------- 256x256 8-phase MFMA GEMM (bf16 operands only) ----------------
// Verified rounds 4/7: 0 bank conflicts, absmax-identical. swz: round-7-verified.
__global__ __launch_bounds__(512) void gemm256(
    const bf16* __restrict__ A, int lda, long sA,
    const bf16* __restrict__ Bv, int ldb, long sB,
    void* __restrict__ C, int cF32, int ldc, long sC,
    int Kc,
    const float* __restrict__ bias, long sBias,
    const void* __restrict__ aux, int auxType, int ldaux, long sAux,
    float accSign, int relu, int swz)
{
    const int z = blockIdx.z;
    const bf16* Ah = A + (long)z * sA;
    const bf16* Bh = Bv + (long)z * sB;
    float* Cf = (float*)C + (long)z * sC;
    bf16*  Ch = (bf16*)C + (long)z * sC;
    const float* biasp = bias ? (bias + (long)z * sBias) : nullptr;
    const float* auxf = (auxType == 1) ? ((const float*)aux + (long)z * sAux) : nullptr;
    const bf16*  auxh = (auxType == 2) ? ((const bf16*)aux + (long)z * sAux) : nullptr;

    __shared__ __align__(16) bf16 As[2][256 * 64];   // 64 KiB
    __shared__ __align__(16) bf16 Bs[2][256 * 64];   // 64 KiB

    const int tid  = threadIdx.x;
    const int lane = tid & 63;
    const int wid  = __builtin_amdgcn_readfirstlane(tid >> 6);
    const int wm   = wid >> 2;          // 0..1  (row half, 128 rows)
    const int wn   = wid & 3;           // 0..3  (col quarter, 64 cols)
    const int lrow = lane & 15;
    const int quad = lane >> 4;
    int bx = blockIdx.x, by = blockIdx.y;
    if (swz) xcd_swz(bx, by);
    const int m0 = bx * 256;
    const int n0 = by * 256;

    // staging: each gll16 covers 8 rows x 128B (wave-uniform LDS base + lane*16B)
    const int srow8  = wid * 8 + (lane >> 3);                    // 0..63
    const int scolsw = ((lane & 7) * 8) ^ ((srow8 & 7) << 3);    // pre-swizzled source col
    const bf16* Aorg = Ah + (long)m0 * lda;
    const bf16* Borg = Bh + (long)n0 * ldb;

    // fragment-read constants (swizzled LDS col; row&7 == lane&7 for all frag rows)
    const int colx = (lane & 7) << 3;
    const int kc0 = (quad * 8) ^ colx;
    const int kc1 = (32 + quad * 8) ^ colx;

    f32x4 acc[8][4] = {};
    s16x8 afr[4][2], bfr[4][2];

    const int nk = Kc >> 6;

    auto stg = [&](const bf16* org, int ld, bf16* lds, int k0, int h) {
#pragma unroll
        for (int j = 0; j < 2; j++) {
            int rl = h * 128 + j * 64 + srow8;
            gll16((const void*)(org + (long)rl * ld + k0 + scolsw),
                  (void*)(lds + (h * 128 + j * 64 + wid * 8) * 64));
        }
    };

    // ---- prologue: stage tiles 0 and 1, wait tile 0 (tile1's 8 loads in flight) ----
    stg(Aorg, lda, As[0], 0, 0); stg(Aorg, lda, As[0], 0, 1);
    stg(Borg, ldb, Bs[0], 0, 0); stg(Borg, ldb, Bs[0], 0, 1);
    if (nk > 1) {
        stg(Aorg, lda, As[1], 64, 0); stg(Aorg, lda, As[1], 64, 1);
        stg(Borg, ldb, Bs[1], 64, 0); stg(Borg, ldb, Bs[1], 64, 1);
        VMC(8);
    } else {
        VMC(0);
    }
    __builtin_amdgcn_s_barrier();

    for (int t = 0; t < nk; ++t) {
        const int s = t & 1;
        const bf16* Acur = As[s];
        const bf16* Bcur = Bs[s];
        bf16* Anxt = As[s ^ 1];
        bf16* Bslot = Bs[s];
        const bool stA = (t >= 1) && (t + 1 < nk);   // A[t+1] (tiles 0,1 staged in prologue)
        const bool stB = (t + 2 < nk);               // B[t+2] into freed B region of slot s

        // ---------- phase 1: af(mi0-3) + bf(ni0-1); stage A[t+1]h0 ----------
#pragma unroll
        for (int mi = 0; mi < 4; mi++) {
            int r = (wm * 128 + mi * 16 + lrow) * 64;
            afr[mi][0] = *(const s16x8*)&Acur[r + kc0];
            afr[mi][1] = *(const s16x8*)&Acur[r + kc1];
        }
#pragma unroll
        for (int ni = 0; ni < 2; ni++) {
            int r = (wn * 64 + ni * 16 + lrow) * 64;
            bfr[ni][0] = *(const s16x8*)&Bcur[r + kc0];
            bfr[ni][1] = *(const s16x8*)&Bcur[r + kc1];
        }
        if (stA) stg(Aorg, lda, Anxt, (t + 1) << 6, 0);
        __builtin_amdgcn_s_barrier();
        LGKM0();
        __builtin_amdgcn_s_setprio(1);
#pragma unroll
        for (int mi = 0; mi < 4; mi++)
#pragma unroll
            for (int ni = 0; ni < 2; ni++)
#pragma unroll
                for (int ks = 0; ks < 2; ks++)
                    acc[mi][ni] = __builtin_amdgcn_mfma_f32_16x16x32_bf16(afr[mi][ks], bfr[ni][ks], acc[mi][ni], 0, 0, 0);
        __builtin_amdgcn_s_setprio(0);
        __builtin_amdgcn_s_barrier();

        // ---------- phase 2: bf(ni2-3); stage A[t+1]h1 ----------
#pragma unroll
        for (int ni = 0; ni < 2; ni++) {
            int r = (wn * 64 + (2 + ni) * 16 + lrow) * 64;
            bfr[2 + ni][0] = *(const s16x8*)&Bcur[r + kc0];
            bfr[2 + ni][1] = *(const s16x8*)&Bcur[r + kc1];
        }
        if (stA) stg(Aorg, lda, Anxt, (t + 1) << 6, 1);
        __builtin_amdgcn_s_barrier();
        LGKM0();
        __builtin_amdgcn_s_setprio(1);
#pragma unroll
        for (int mi = 0; mi < 4; mi++)
#pragma unroll
            for (int ni = 0; ni < 2; ni++)
#pragma unroll
                for (int ks = 0; ks < 2; ks++)
                    acc[mi][2 + ni] = __builtin_amdgcn_mfma_f32_16x16x32_bf16(afr[mi][ks], bfr[2 + ni][ks], acc[mi][2 + ni], 0, 0, 0);
        __builtin_amdgcn_s_setprio(0);
        __builtin_amdgcn_s_barrier();

        // ---------- phase 3: af(mi4-7); stage B[t+2]h0 (B[t] reads drained at ph2 barrier) ----------
#pragma unroll
        for (int mi = 0; mi < 4; mi++) {
            int r = (wm * 128 + 64 + mi * 16 + lrow) * 64;
            afr[mi][0] = *(const s16x8*)&Acur[r + kc0];
            afr[mi][1] = *(const s16x8*)&Acur[r + kc1];
        }
        if (stB) stg(Borg, ldb, Bslot, (t + 2) << 6, 0);
        __builtin_amdgcn_s_barrier();
        LGKM0();
        __builtin_amdgcn_s_setprio(1);
#pragma unroll
        for (int mi = 0; mi < 4; mi++)
#pragma unroll
            for (int ni = 0; ni < 2; ni++)
#pragma unroll
                for (int ks = 0; ks < 2; ks++)
                    acc[4 + mi][ni] = __builtin_amdgcn_mfma_f32_16x16x32_bf16(afr[mi][ks], bfr[ni][ks], acc[4 + mi][ni], 0, 0, 0);
        __builtin_amdgcn_s_setprio(0);
        __builtin_amdgcn_s_barrier();

        // ---------- phase 4: no reads; stage B[t+2]h1; counted vmcnt ----------
        if (stB) stg(Borg, ldb, Bslot, (t + 2) << 6, 1);
        __builtin_amdgcn_s_barrier();
        __builtin_amdgcn_s_setprio(1);
#pragma unroll
        for (int mi = 0; mi < 4; mi++)
#pragma unroll
            for (int ni = 0; ni < 2; ni++)
#pragma unroll
                for (int ks = 0; ks < 2; ks++)
                    acc[4 + mi][2 + ni] = __builtin_amdgcn_mfma_f32_16x16x32_bf16(afr[mi][ks], bfr[2 + ni][ks], acc[4 + mi][2 + ni], 0, 0, 0);
        __builtin_amdgcn_s_setprio(0);
        // vmcnt(4): tile t+1 (A+B, 8 oldest) drained; B[t+2]'s 4 loads stay in flight
        if (stB) { VMC(4); } else { VMC(0); }
        __builtin_amdgcn_s_barrier();
    }

    // epilogue: C/D layout col = lane&15, row = quad*4 + i (verified)
#pragma unroll
    for (int mi = 0; mi < 8; mi++) {
#pragma unroll
        for (int ni = 0; ni < 4; ni++) {
            int col = n0 + wn * 64 + ni * 16 + lrow;
            float bvl = biasp ? biasp[col] : 0.0f;
#pragma unroll
            for (int i = 0; i < 4; i++) {
                int row = m0 + wm * 128 + mi * 16 + quad * 4 + i;
                float v = accSign * acc[mi][ni][i] + bvl;
                if (auxType == 1) v += auxf[(long)row * ldaux + col];
                else if (auxType == 2) v += (float)auxh[(long)row * ldaux + col];
                if (relu) v = fmaxf(v, 0.0f);
                if (cF32) Cf[(long)row * ldc + col] = v;
                else Ch[(long)row * ldc + col] = (bf16)v;
            }
        }
    }
}

// ---------------- 128-tile MFMA GEMM ----------------
// bf16 path: 3-buffer 2-deep prefetch, raw builtin s_barrier + counted vmcnt
// (T4, m218 — confirmed a win round 6). NO XCD swizzle (round-7 lesson).
template<int BN>
__global__ __launch_bounds__(256) void gemm_nt(
    const void* __restrict__ A, int aF32, int lda, long sA,
    const void* __restrict__ Bv, int bF32, int ldb, long sB,
    void* __restrict__ C, int cF32, int ldc, long sC,
    int Kc,
    const float* __restrict__ bias, long sBias,
    const void* __restrict__ aux, int auxType, int ldaux, long sAux,
    float accSign, int relu)
{
    constexpr int NI = BN / 32;   // B fragments per wave
    constexpr int WN = BN / 2;    // cols per wn-wave
    const int z = blockIdx.z;
    const float* Af = (const float*)A + (long)z * sA;
    const bf16*  Ah = (const bf16*)A + (long)z * sA;
    const float* Bf = (const float*)Bv + (long)z * sB;
    const bf16*  Bh = (const bf16*)Bv + (long)z * sB;
    float* Cf = (float*)C + (long)z * sC;
    bf16*  Ch = (bf16*)C + (long)z * sC;
    const float* biasp = bias ? (bias + (long)z * sBias) : nullptr;
    const float* auxf = (auxType == 1) ? ((const float*)aux + (long)z * sAux) : nullptr;
    const bf16*  auxh = (auxType == 2) ? ((const bf16*)aux + (long)z * sAux) : nullptr;

    __shared__ __align__(16) bf16 As[3][128 * 32];
    __shared__ __align__(16) bf16 Bs[3][BN * 32];

    const int tid = threadIdx.x;
    const int lane = tid & 63;
    const int wv = __builtin_amdgcn_readfirstlane(tid >> 6);
    const int wm = (tid >> 6) & 1;
    const int wn = (tid >> 6) >> 1;
    const int lrow = lane & 15;
    const int quad = lane >> 4;
    const int m0 = blockIdx.x * 128;
    const int n0 = blockIdx.y * BN;
    const int srow = tid >> 1;
    const int scol = (tid & 1) * 16;
    const int drow = wv * 16 + (lane >> 2);
    const int dcol = (lane & 3) * 8;

    f32x4 acc[4][NI] = {};

    if (!aF32 && !bF32) {
        // bf16 operands: 3-buffer counted-vmcnt pipeline
        const int nk = Kc >> 5;
        auto stage = [&](int t) {
            const int buf = t % 3;
            const int k0 = t << 5;
            const bf16* a0 = Ah + (long)(m0 + drow) * lda + k0 + dcol;
            gll16((const void*)a0, (void*)&As[buf][wv * 512]);
            gll16((const void*)(a0 + (long)lda * 64), (void*)&As[buf][2048 + wv * 512]);
            const bf16* b0 = Bh + (long)(n0 + drow) * ldb + k0 + dcol;
            gll16((const void*)b0, (void*)&Bs[buf][wv * 512]);
            if (BN == 128)
                gll16((const void*)(b0 + (long)ldb * 64), (void*)&Bs[buf][2048 + wv * 512]);
        };
        stage(0);
        if (nk > 1) {
            stage(1);
            if constexpr (BN == 128) { VMC(4); } else { VMC(3); }
        } else {
            VMC(0);
        }
        __builtin_amdgcn_s_barrier();
        for (int t = 0; t < nk; ++t) {
            const int cur = t % 3;
            if (t + 2 < nk) stage(t + 2);
            s16x8 af[4], bfg[NI];
#pragma unroll
            for (int mi = 0; mi < 4; mi++)
                af[mi] = *(const s16x8*)&As[cur][(wm * 64 + mi * 16 + lrow) * 32 + quad * 8];
#pragma unroll
            for (int ni = 0; ni < NI; ni++)
                bfg[ni] = *(const s16x8*)&Bs[cur][(wn * WN + ni * 16 + lrow) * 32 + quad * 8];
#pragma unroll
            for (int mi = 0; mi < 4; mi++)
#pragma unroll
                for (int ni = 0; ni < NI; ni++)
                    acc[mi][ni] = __builtin_amdgcn_mfma_f32_16x16x32_bf16(af[mi], bfg[ni], acc[mi][ni], 0, 0, 0);
            // drain stage(t+1) (oldest L), keep stage(t+2) in flight
            if (t + 2 < nk) {
                if constexpr (BN == 128) { VMC(4); } else { VMC(3); }
            } else {
                VMC(0);
            }
            __builtin_amdgcn_s_barrier();
        }
    } else {
        // f32 or mixed operands, single buffer (bf16 side staged via gll)
        for (int k0 = 0; k0 < Kc; k0 += 32) {
            uint4 av0, av1, bv0, bv1;
            if (aF32) {
                const float* ag = Af + (long)(m0 + srow) * lda + k0 + scol;
                ushort t[16];
#pragma unroll
                for (int j = 0; j < 4; j++) {
                    float4 f = *(const float4*)(ag + 4 * j);
                    t[4*j] = f2b(f.x); t[4*j+1] = f2b(f.y); t[4*j+2] = f2b(f.z); t[4*j+3] = f2b(f.w);
                }
                av0 = *(const uint4*)&t[0]; av1 = *(const uint4*)&t[8];
            }
            if (bF32) {
                if (srow < BN) {
                    const float* bg = Bf + (long)(n0 + srow) * ldb + k0 + scol;
                    ushort t[16];
#pragma unroll
                    for (int j = 0; j < 4; j++) {
                        float4 f = *(const float4*)(bg + 4 * j);
                        t[4*j] = f2b(f.x); t[4*j+1] = f2b(f.y); t[4*j+2] = f2b(f.z); t[4*j+3] = f2b(f.w);
                    }
                    bv0 = *(const uint4*)&t[0]; bv1 = *(const uint4*)&t[8];
                }
            }
            __syncthreads();
            if (aF32) {
                *(uint4*)&As[0][srow * 32 + scol] = av0;
                *(uint4*)&As[0][srow * 32 + scol + 8] = av1;
            } else {
                gll16((const void*)(Ah + (long)(m0 + drow) * lda + k0 + dcol), (void*)&As[0][wv * 512]);
                gll16((const void*)(Ah + (long)(m0 + 64 + drow) * lda + k0 + dcol), (void*)&As[0][2048 + wv * 512]);
            }
            if (bF32) {
                if (srow < BN) {
                    *(uint4*)&Bs[0][srow * 32 + scol] = bv0;
                    *(uint4*)&Bs[0][srow * 32 + scol + 8] = bv1;
                }
            } else {
                gll16((const void*)(Bh + (long)(n0 + drow) * ldb + k0 + dcol), (void*)&Bs[0][wv * 512]);
                if (BN == 128)
                    gll16((const void*)(Bh + (long)(n0 + 64 + drow) * ldb + k0 + dcol), (void*)&Bs[0][2048 + wv * 512]);
            }
            __syncthreads();

            s16x8 af[4], bfg[NI];
#pragma unroll
            for (int mi = 0; mi < 4; mi++)
                af[mi] = *(const s16x8*)&As[0][(wm * 64 + mi * 16 + lrow) * 32 + quad * 8];
#pragma unroll
            for (int ni = 0; ni < NI; ni++)
                bfg[ni] = *(const s16x8*)&Bs[0][(wn * WN + ni * 16 + lrow) * 32 + quad * 8];
#pragma unroll
            for (int mi = 0; mi < 4; mi++)
#pragma unroll
                for (int ni = 0; ni < NI; ni++)
                    acc[mi][ni] = __builtin_amdgcn_mfma_f32_16x16x32_bf16(af[mi], bfg[ni], acc[mi][ni], 0, 0, 0);
        }
    }

    // epilogue
#pragma unroll
    for (int mi = 0; mi < 4; mi++) {
#pragma unroll
        for (int ni = 0; ni < NI; ni++) {
            int col = n0 + wn * WN + ni * 16 + lrow;
            float bvl = biasp ? biasp[col] : 0.0f;
#pragma unroll
            for (int i = 0; i < 4; i++) {
                int row = m0 + wm * 64 + mi * 16 + quad * 4 + i;
                float v = accSign * acc[mi][ni][i] + bvl;
                if (auxType == 1) v += auxf[(long)row * ldaux + col];
                else if (auxType == 2) v += (float)auxh[(long)row * ldaux + col];
                if (relu) v = fmaxf(v, 0.0f);
                if (cF32) Cf[(long)row * ldc + col] = v;
                else Ch[(long)row * ldc + col] = (bf16)v;
            }
        }
    }
}

// ---------------- conversions ----------------
__global__ __launch_bounds__(256) void cvt4(const float* __restrict__ in, bf16* __restrict__ out, int n4) {
    int i = blockIdx.x * 256 + threadIdx.x;
    if (i < n4) {
        float4 f = ((const float4*)in)[i];
        ushort4 u; u.x = f2b(f.x); u.y = f2b(f.y); u.z = f2b(f.z); u.w = f2b(f.w);
        ((ushort4*)out)[i] = u;
    }
}

struct WCvt {
    const float* in[16];
    bf16* out[16];
    int n4[16];
};
__global__ __launch_bounds__(256) void cvt_weights(WCvt wc) {
    int t = blockIdx.y;
    int n4 = wc.n4[t];
    const float4* in = (const float4*)wc.in[t];
    ushort4* out = (ushort4*)wc.out[t];
    for (int i = blockIdx.x * 256 + threadIdx.x; i < n4; i += gridDim.x * 256) {
        float4 f = in[i];
        ushort4 u; u.x = f2b(f.x); u.y = f2b(f.y); u.z = f2b(f.z); u.w = f2b(f.w);
        out[i] = u;
    }
}

// ---------------- elementwise / normalization ----------------
__global__ __launch_bounds__(256) void l2norm_rows(bf16* __restrict__ Q) {
    bf16* q = Q + (long)blockIdx.x * KF;
    ushort4 u = ((ushort4*)q)[threadIdx.x];
    float v0 = b2f(u.x), v1 = b2f(u.y), v2 = b2f(u.z), v3 = b2f(u.w);
    float ss = blockReduceSum(v0 * v0 + v1 * v1 + v2 * v2 + v3 * v3);
    float inv = 1.0f / fmaxf(sqrtf(ss), 1e-12f);
    u.x = f2b(v0 * inv); u.y = f2b(v1 * inv); u.z = f2b(v2 * inv); u.w = f2b(v3 * inv);
    ((ushort4*)q)[threadIdx.x] = u;
}

// merged Q/K l2norm, planar layout: plane y (0=Q, 1=K), row x
__global__ __launch_bounds__(256) void l2norm2(bf16* __restrict__ QK) {
    bf16* q = QK + (long)blockIdx.y * ((long)NN * KF) + (long)blockIdx.x * KF;
    ushort4 u = ((ushort4*)q)[threadIdx.x];
    float v0 = b2f(u.x), v1 = b2f(u.y), v2 = b2f(u.z), v3 = b2f(u.w);
    float ss = blockReduceSum(v0 * v0 + v1 * v1 + v2 * v2 + v3 * v3);
    float inv = 1.0f / fmaxf(sqrtf(ss), 1e-12f);
    u.x = f2b(v0 * inv); u.y = f2b(v1 * inv); u.z = f2b(v2 * inv); u.w = f2b(v3 * inv);
    ((ushort4*)q)[threadIdx.x] = u;
}

__global__ __launch_bounds__(256) void softmax_rows(bf16* __restrict__ P) {
    bf16* p = P + (long)blockIdx.x * LL;
    ushort4 a = ((ushort4*)p)[2 * threadIdx.x];
    ushort4 b = ((ushort4*)p)[2 * threadIdx.x + 1];
    float v[8] = {b2f(a.x), b2f(a.y), b2f(a.z), b2f(a.w), b2f(b.x), b2f(b.y), b2f(b.z), b2f(b.w)};
    float mx = -1e30f;
#pragma unroll
    for (int i = 0; i < 8; i++) mx = fmaxf(mx, v[i]);
    mx = blockReduceMax(mx);
    float s = 0.0f;
#pragma unroll
    for (int i = 0; i < 8; i++) { v[i] = __expf(v[i] - mx); s += v[i]; }
    s = blockReduceSum(s);
    float inv = 1.0f / s;
    a.x = f2b(v[0]*inv); a.y = f2b(v[1]*inv); a.z = f2b(v[2]*inv); a.w = f2b(v[3]*inv);
    b.x = f2b(v[4]*inv); b.y = f2b(v[5]*inv); b.z = f2b(v[6]*inv); b.w = f2b(v[7]*inv);
    ((ushort4*)p)[2 * threadIdx.x] = a;
    ((ushort4*)p)[2 * threadIdx.x + 1] = b;
}

__global__ __launch_bounds__(256) void zero_cs(float* __restrict__ cs) {
    cs[blockIdx.x * 256 + threadIdx.x] = 0.0f;
}

__global__ __launch_bounds__(256) void colsum2(const bf16* __restrict__ P, float* __restrict__ cs) {
    int col = blockIdx.x * 256 + threadIdx.x;
    int rc = blockIdx.y;
    int b = blockIdx.z;
    const bf16* p = P + (long)b * LL * LL + (long)rc * 128 * LL + col;
    float s = 0.0f;
#pragma unroll 4
    for (int r = 0; r < 128; r++) s += (float)p[(long)r * LL];
    atomicAdd(&cs[(long)b * LL + col], s);
}

__global__ __launch_bounds__(256) void scale_vt(bf16* __restrict__ vt, const float* __restrict__ cs) {
    int e = blockIdx.x, b = blockIdx.y;
    bf16* row = vt + ((long)b * DM + e) * LL;
    const float* c = cs + (long)b * LL;
#pragma unroll
    for (int i = 0; i < 8; i++) {
        int m = threadIdx.x + i * 256;
        row[m] = (bf16)((float)row[m] / (1e-9f + c[m]));
    }
}

__global__ __launch_bounds__(256) void ln_rows(const bf16* __restrict__ in, void* __restrict__ out,
                                               int outF32,
                                               const float* __restrict__ g, const float* __restrict__ b,
                                               const float* __restrict__ aux) {
    long base = (long)blockIdx.x * 256;
    float v = (float)in[base + threadIdx.x];
    if (aux) v += aux[base + threadIdx.x];
    float mean = blockReduceSum(v) * (1.0f / 256.0f);
    float d = v - mean;
    float var = blockReduceSum(d * d) * (1.0f / 256.0f);
    float o = d * rsqrtf(var + 1e-5f) * g[threadIdx.x] + b[threadIdx.x];
    if (outF32) ((float*)out)[base + threadIdx.x] = o;
    else ((bf16*)out)[base + threadIdx.x] = (bf16)o;
}

__global__ __launch_bounds__(256) void ln_cat(bf16* __restrict__ cat, const float* __restrict__ g,
                                              const float* __restrict__ bb) {
    long n = blockIdx.x;
    int h = blockIdx.y;
    bf16* x = cat + n * HD + (long)h * DM;
    float v = (float)x[threadIdx.x];
    float mean = blockReduceSum(v) * (1.0f / 256.0f);
    float d = v - mean;
    float var = blockReduceSum(d * d) * (1.0f / 256.0f);
    x[threadIdx.x] = (bf16)(d * rsqrtf(var + 1e-5f) * g[h * DM + threadIdx.x] + bb[h * DM + threadIdx.x]);
}

// ---------------- host ----------------
extern "C" void kernel_launch(void* const* d_in, const int* in_sizes, int n_in,
                              void* d_out, int out_size, void* d_ws, size_t ws_size,
                              hipStream_t stream) {
    const float* src  = (const float*)d_in[0];
    const float* WK   = (const float*)d_in[1];
    const float* WQ   = (const float*)d_in[2];
    const float* WV   = (const float*)d_in[3];
    const float* TC   = (const float*)d_in[4];
    const float* ENw1 = (const float*)d_in[5];
    const float* ENb1 = (const float*)d_in[6];
    const float* ENw2 = (const float*)d_in[7];
    const float* ENb2 = (const float*)d_in[8];
    const float* ENg  = (const float*)d_in[9];
    const float* ENbt = (const float*)d_in[10];
    const float* Wout = (const float*)d_in[11];
    const float* L1w  = (const float*)d_in[12];
    const float* L1b  = (const float*)d_in[13];
    const float* L2w  = (const float*)d_in[14];
    const float* L2b  = (const float*)d_in[15];
    const float* N1g  = (const float*)d_in[16];
    const float* N1b  = (const float*)d_in[17];
    const float* N2g  = (const float*)d_in[18];
    const float* N2b  = (const float*)d_in[19];

    const size_t COMPACT_FLOOR = 34700000;
    const size_t FAST_FLOOR  = 92307456;
    const size_t FASTW_FLOOR = 92307456 + 11010048;
    if (ws_size < COMPACT_FLOOR || out_size != NN * DM || n_in != 20) {
        float val;
        if (n_in != 20) val = 32768.0f + (float)n_in;
        else if (out_size != NN * DM) val = 49152.0f;
        else val = 16384.0f + 128.0f * (float)(unsigned)(ws_size >> 20);
        sentinel_kernel<<<1, 64, 0, stream>>>((float*)d_out, val);
        return;
    }

    char* w = (char*)d_ws;
    auto G = [&](const void* A, int aF, int lda, long sA,
                 const void* B, int bF, int ldb, long sB,
                 void* C, int cF, int ldc, long sC,
                 int M, int Nn, int Kc, int nb,
                 const float* bias, long sBias,
                 const void* aux, int auxT, int ldaux, long sAux,
                 float sgn, int relu) {
        gemm_nt<128><<<dim3(M / 128, Nn / 128, nb), dim3(256), 0, stream>>>(
            A, aF, lda, sA, B, bF, ldb, sB, C, cF, ldc, sC, Kc,
            bias, sBias, aux, auxT, ldaux, sAux, sgn, relu);
    };
    auto G64 = [&](const void* A, int aF, int lda, long sA,
                 const void* B, int bF, int ldb, long sB,
                 void* C, int cF, int ldc, long sC,
                 int M, int Nn, int Kc, int nb,
                 const float* bias, long sBias,
                 const void* aux, int auxT, int ldaux, long sAux,
                 float sgn, int relu) {
        gemm_nt<64><<<dim3(M / 128, Nn / 64, nb), dim3(256), 0, stream>>>(
            A, aF, lda, sA, B, bF, ldb, sB, C, cF, ldc, sC, Kc,
            bias, sBias, aux, auxT, ldaux, sAux, sgn, relu);
    };
    auto G2 = [&](const void* A, int lda, long sA,
                  const void* B, int ldb, long sB,
                  void* C, int cF, int ldc, long sC,
                  int M, int Nn, int Kc, int nb,
                  const float* bias, long sBias,
                  const void* aux, int auxT, int ldaux, long sAux,
                  float sgn, int relu) {
        gemm256<<<dim3(M / 256, Nn / 256, nb), dim3(512), 0, stream>>>(
            (const bf16*)A, lda, sA, (const bf16*)B, ldb, sB, C, cF, ldc, sC, Kc,
            bias, sBias, aux, auxT, ldaux, sAux, sgn, relu, 1);
    };

    if (ws_size >= FAST_FLOOR) {
        // ======== FAST PATH ========
        bf16*  Sb  = (bf16*)(w + 0);
        bf16*  Q   = (bf16*)(w + 4194304);     // 16 MB, planar
        bf16*  K   = (bf16*)(w + 20971520);    // 16 MB, planar (= Q + NN*KF elems)
        bf16*  Vt  = (bf16*)(w + 37748736);
        bf16*  P   = (bf16*)(w + 41943040);
        bf16*  Su  = (bf16*)(w + 75497472);
        float* Cs  = (float*)(w + 92274688);
        bf16* Ru = Q; bf16* Hid = K; bf16* Cat = P;
        bf16* Attn = Vt; bf16* Xln = Su; bf16* Ffh = Q; bf16* Yp = Vt;

        const int haveWb = (ws_size >= FASTW_FLOOR) ? 1 : 0;
        char* wb = w + 92307456;
        bf16* WQKb  = (bf16*)(wb + 0);          // 4MB: per head [WQ_h(1024x256); WK_h(1024x256)]
        bf16* WVb   = (bf16*)(wb + 4194304);
        bf16* TCb   = (bf16*)(wb + 4718592);
        bf16* ENw1b = (bf16*)(wb + 5242880);
        bf16* ENw2b = (bf16*)(wb + 7340032);
        bf16* Woutb = (bf16*)(wb + 9437184);
        bf16* L1wb  = (bf16*)(wb + 9961472);
        bf16* L2wb  = (bf16*)(wb + 10485760);
        if (haveWb) {
            WCvt wc;
            for (int h = 0; h < HN; h++) {
                wc.in[2*h]   = WQ + (long)h * KF * DM; wc.out[2*h]   = WQKb + (long)h * 2048 * DM;            wc.n4[2*h]   = 65536;
                wc.in[2*h+1] = WK + (long)h * KF * DM; wc.out[2*h+1] = WQKb + (long)h * 2048 * DM + KF * DM;  wc.n4[2*h+1] = 65536;
            }
            wc.in[8]  = WV;   wc.out[8]  = WVb;   wc.n4[8]  = 65536;
            wc.in[9]  = TC;   wc.out[9]  = TCb;   wc.n4[9]  = 65536;
            wc.in[10] = ENw1; wc.out[10] = ENw1b; wc.n4[10] = 262144;
            wc.in[11] = ENw2; wc.out[11] = ENw2b; wc.n4[11] = 262144;
            wc.in[12] = Wout; wc.out[12] = Woutb; wc.n4[12] = 65536;
            wc.in[13] = L1w;  wc.out[13] = L1wb;  wc.n4[13] = 65536;
            wc.in[14] = L2w;  wc.out[14] = L2wb;  wc.n4[14] = 65536;
            cvt_weights<<<dim3(256, 15), 256, 0, stream>>>(wc);
        }
        const int wF = haveWb ? 0 : 1;
        auto WP = [&](const void* f32p, const void* b16p, long off) {
            return haveWb ? (const void*)((const bf16*)b16p + off)
                          : (const void*)((const float*)f32p + off);
        };

        cvt4<<<2048, 256, 0, stream>>>(src, Sb, NN * DM / 4);

        for (int h = 0; h < HN; h++) {
            if (haveWb) {
                // merged Q+K projection via z-batch: z=0 -> WQ_h -> Q plane,
                // z=1 -> WK_h -> K plane. Planar outputs keep the P-GEMM's
                // 8KB row stride (round-6 lesson: 16KB stride cost 35% BW).
                // grid (32,4,2) = 256 blocks = full GPU.
                G2(Sb, DM, 0, WQKb + (long)h * 2048 * DM, DM, (long)KF * DM,
                   Q, 0, KF, (long)NN * KF,
                   NN, KF, DM, 2, nullptr, 0, nullptr, 0, 0, 0, 1.0f, 0);
            } else {
                G(Sb, 0, DM, 0, WQ + (long)h * KF * DM, 1, DM, 0, Q, 0, KF, 0,
                  NN, KF, DM, 1, nullptr, 0, nullptr, 0, 0, 0, 1.0f, 0);
                G(Sb, 0, DM, 0, WK + (long)h * KF * DM, 1, DM, 0, K, 0, KF, 0,
                  NN, KF, DM, 1, nullptr, 0, nullptr, 0, 0, 0, 1.0f, 0);
            }
            G64(WP(WV, WVb, (long)h * DM * DM), wF, DM, 0, Sb, 0, BB * DM, DM,
              Vt, 0, LL, (long)DM * LL,
              DM, LL, DM, BB, nullptr, 0, nullptr, 0, 0, 0, 1.0f, 0);
            l2norm2<<<dim3(NN, 2), 256, 0, stream>>>(Q);
            // P = Q K^T, separate planar Q/K (round-7 verified: swz gemm256 -> 49.8us)
            G2(Q, BB * KF, KF, K, BB * KF, KF, P, 0, LL, (long)LL * LL,
               LL, LL, KF, BB, nullptr, 0, nullptr, 0, 0, 0, 1.0f, 0);
            softmax_rows<<<BB * LL, 256, 0, stream>>>(P);
            zero_cs<<<BB * LL / 256, 256, 0, stream>>>(Cs);
            colsum2<<<dim3(LL / 256, 16, BB), 256, 0, stream>>>(P, Cs);
            scale_vt<<<dim3(DM, BB), 256, 0, stream>>>(Vt, Cs);
            G64(P, 0, LL, (long)LL * LL, Vt, 0, LL, (long)DM * LL,
              Su + (long)h * NN * DM, 0, BB * DM, DM,
              LL, DM, LL, BB, nullptr, 0, Sb, 2, BB * DM, DM, -1.0f, 0);
        }
        G(Su, 0, DM, (long)NN * DM, WP(TC, TCb, 0), wF, DM, (long)DM * DM,
          Ru, 0, DM, (long)NN * DM,
          NN, DM, DM, HN, nullptr, 0, nullptr, 0, 0, 0, 1.0f, 1);
        for (int h = 0; h < HN; h++) {
            G(Ru + (long)h * NN * DM, 0, DM, 0, WP(ENw1, ENw1b, (long)h * FFD * DM), wF, DM, 0,
              Hid, 0, FFD, 0, NN, FFD, DM, 1, ENb1 + (long)h * FFD, 0, nullptr, 0, 0, 0, 1.0f, 1);
            G64(Hid, 0, FFD, 0, WP(ENw2, ENw2b, (long)h * DM * FFD), wF, FFD, 0,
              Cat + (long)h * DM, 0, HD, 0, NN, DM, FFD, 1,
              ENb2 + (long)h * DM, 0, Ru + (long)h * NN * DM, 2, DM, 0, 1.0f, 0);
        }
        ln_cat<<<dim3(NN, HN), 256, 0, stream>>>(Cat, ENg, ENbt);
        G64(Cat, 0, HD, 0, WP(Wout, Woutb, 0), wF, HD, 0, Attn, 0, DM, 0,
          NN, DM, HD, 1, nullptr, 0, nullptr, 0, 0, 0, 1.0f, 0);
        ln_rows<<<NN, 256, 0, stream>>>(Attn, Xln, 0, N1g, N1b, src);
        G(Xln, 0, DM, 0, WP(L1w, L1wb, 0), wF, DM, 0, Ffh, 0, FFD, 0,
          NN, FFD, DM, 1, L1b, 0, nullptr, 0, 0, 0, 1.0f, 1);
        G64(Ffh, 0, FFD, 0, WP(L2w, L2wb, 0), wF, FFD, 0, Yp, 0, DM, 0,
          NN, DM, FFD, 1, L2b, 0, Xln, 2, DM, 0, 1.0f, 0);
        ln_rows<<<NN, 256, 0, stream>>>(Yp, (float*)d_out, 1, N2g, N2b, nullptr);
    } else {
        // ======== COMPACT PATH ========
        bf16*  S0 = (bf16*)(w + 0);
        bf16*  S1 = (bf16*)(w + 16777216);
        bf16*  S2 = (bf16*)(w + 20971520);
        bf16*  S3 = (bf16*)(w + 25165824);
        bf16*  S4 = (bf16*)(w + 26214400);
        bf16*  S5 = (bf16*)(w + 30408704);
        float* Cs = (float*)(w + 34603008);

        for (int h = 0; h < HN; h++) {
            for (int b = 0; b < BB; b++) {
                G(src + b * DM, 1, BB * DM, 0, WQ + (long)h * KF * DM, 1, DM, 0,
                  S1, 0, KF, 0, LL, KF, DM, 1, nullptr, 0, nullptr, 0, 0, 0, 1.0f, 0);
                G(src + b * DM, 1, BB * DM, 0, WK + (long)h * KF * DM, 1, DM, 0,
                  S2, 0, KF, 0, LL, KF, DM, 1, nullptr, 0, nullptr, 0, 0, 0, 1.0f, 0);
                G(WV + (long)h * DM * DM, 1, DM, 0, src + b * DM, 1, BB * DM, 0,
                  S3, 0, LL, 0, DM, LL, DM, 1, nullptr, 0, nullptr, 0, 0, 0, 1.0f, 0);
                l2norm_rows<<<LL, 256, 0, stream>>>(S1);
                l2norm_rows<<<LL, 256, 0, stream>>>(S2);
                G(S1, 0, KF, 0, S2, 0, KF, 0, S0, 0, LL, 0,
                  LL, LL, KF, 1, nullptr, 0, nullptr, 0, 0, 0, 1.0f, 0);
                softmax_rows<<<LL, 256, 0, stream>>>(S0);
                zero_cs<<<LL / 256, 256, 0, stream>>>(Cs);
                colsum2<<<dim3(LL / 256, 16, 1), 256, 0, stream>>>(S0, Cs);
                scale_vt<<<dim3(DM, 1), 256, 0, stream>>>(S3, Cs);
                G(S0, 0, LL, 0, S3, 0, LL, 0, S4 + b * DM, 0, BB * DM, 0,
                  LL, DM, LL, 1, nullptr, 0, src + b * DM, 1, BB * DM, 0, -1.0f, 0);
            }
            G(S4, 0, DM, 0, TC + (long)h * DM * DM, 1, DM, 0, S1, 0, DM, 0,
              NN, DM, DM, 1, nullptr, 0, nullptr, 0, 0, 0, 1.0f, 1);
            G(S1, 0, DM, 0, ENw1 + (long)h * FFD * DM, 1, DM, 0, S0, 0, FFD, 0,
              NN, FFD, DM, 1, ENb1 + (long)h * FFD, 0, nullptr, 0, 0, 0, 1.0f, 1);
            G(S0, 0, FFD, 0, ENw2 + (long)h * DM * FFD, 1, FFD, 0, S2, 0, DM, 0,
              NN, DM, FFD, 1, ENb2 + (long)h * DM, 0, S1, 2, DM, 0, 1.0f, 0);
            ln_rows<<<NN, 256, 0, stream>>>(S2, S2, 0, ENg + (long)h * DM, ENbt + (long)h * DM, nullptr);
            G(S2, 0, DM, 0, Wout + (long)h * DM, 1, HD, 0, S5, 0, DM, 0,
              NN, DM, DM, 1, nullptr, 0, (h == 0) ? nullptr : (const void*)S5,
              (h == 0) ? 0 : 2, DM, 0, 1.0f, 0);
        }
        ln_rows<<<NN, 256, 0, stream>>>(S5, S1, 0, N1g, N1b, src);
        G(S1, 0, DM, 0, L1w, 1, DM, 0, S0, 0, FFD, 0,
          NN, FFD, DM, 1, L1b, 0, nullptr, 0, 0, 0, 1.0f, 1);
        G(S0, 0, FFD, 0, L2w, 1, FFD, 0, S2, 0, DM, 0,
          NN, DM, FFD, 1, L2b, 0, S1, 2, DM, 0, 1.0f, 0);
        ln_rows<<<NN, 256, 0, stream>>>(S2, (float*)d_out, 1, N2g, N2b, nullptr);
    }
}